// Round 2
// baseline (3654.855 us; speedup 1.0000x reference)
//
#include <hip/hip_runtime.h>
#include <hip/hip_bf16.h>

// Block_4776003633552: transformer block, B=4 T=2048 C=512 H=8 D=64.
// I/O: fp32 device buffers (values bf16-rounded by the dataset; tolerance 2%+bf16 floor).
// Reference quirks reproduced: scale = C^-0.5 (not D^-0.5); softmax over the
// QUERY axis (axis=-2) => column softmax: out_t = sum_{s<=t} exp(sc*q_t.k_s) * v_s / L_s,
// L_s = sum_{t>=s} exp(sc*q_t.k_s).
// Round 2: fp32 I/O, bf16 intermediates in workspace, VALU compute baseline.

typedef __hip_bfloat16 bf16;

#define B_   4
#define T_   2048
#define C_   512
#define H_   8
#define D_   64
#define BT_  (B_ * T_)
#define C4_  (4 * C_)
#define EPS_ 1e-5f
#define SCALE_ 0.04419417382415922f  // 1/sqrt(512)

static __device__ __forceinline__ float b2f(bf16 x) { return __bfloat162float(x); }
static __device__ __forceinline__ bf16  f2b(float x) { return __float2bfloat16(x); }

static __device__ __forceinline__ float ldv(const float* p) { return *p; }
static __device__ __forceinline__ float ldv(const bf16* p)  { return b2f(*p); }
static __device__ __forceinline__ void  stv(float* p, float v) { *p = v; }
static __device__ __forceinline__ void  stv(bf16* p, float v)  { *p = f2b(v); }

// ---------------- LayerNorm over C=512, one block per row, 256 threads ----------------
// x: TIN (fp32 input or bf16 ws), g/be: fp32 inputs, out: bf16 ws.
template <typename TIN>
__global__ __launch_bounds__(256) void ln_kernel(const TIN* __restrict__ x,
                                                 const float* __restrict__ g,
                                                 const float* __restrict__ be,
                                                 bf16* __restrict__ out) {
    const int row = blockIdx.x;
    const int tid = threadIdx.x;
    const TIN* xr = x + (size_t)row * C_;
    float v0 = ldv(xr + tid * 2);
    float v1 = ldv(xr + tid * 2 + 1);
    float s = v0 + v1;
    float sq = v0 * v0 + v1 * v1;
    #pragma unroll
    for (int o = 32; o > 0; o >>= 1) {
        s += __shfl_down(s, o);
        sq += __shfl_down(sq, o);
    }
    __shared__ float ws[8], wsq[8];
    const int wid = tid >> 6, lane = tid & 63;
    if (lane == 0) { ws[wid] = s; wsq[wid] = sq; }
    __syncthreads();
    if (tid == 0) {
        float ts = 0.f, tq = 0.f;
        #pragma unroll
        for (int i = 0; i < 4; i++) { ts += ws[i]; tq += wsq[i]; }
        float mu = ts * (1.f / C_);
        float var = tq * (1.f / C_) - mu * mu;
        ws[4] = mu;
        wsq[4] = rsqrtf(var + EPS_);
    }
    __syncthreads();
    const float mu = ws[4], rstd = wsq[4];
    bf16* orow = out + (size_t)row * C_;
    orow[tid * 2]     = f2b((v0 - mu) * rstd * g[tid * 2]     + be[tid * 2]);
    orow[tid * 2 + 1] = f2b((v1 - mu) * rstd * g[tid * 2 + 1] + be[tid * 2 + 1]);
}

// ---------------- Generic GEMM: C[M,N] = A[M,K]@B[K,N] (+bias)(+relu)(+res) ----------------
// A: bf16 ws. Bw/bias: fp32 inputs. res: TR (fp32 input x or bf16 ws). out: TO.
// 64x64 tile, BK=16, 256 threads (16x16), 4x4 microtile, fp32 accum.
template <bool BIAS, bool RES, bool RELU, typename TR, typename TO>
__global__ __launch_bounds__(256) void gemm_kernel(const bf16* __restrict__ A,
                                                   const float* __restrict__ Bw,
                                                   const float* __restrict__ bias,
                                                   const TR* __restrict__ res,
                                                   TO* __restrict__ Cm,
                                                   int M, int N, int K) {
    __shared__ bf16 As[64][17];
    __shared__ bf16 Bs[16][64];
    const int tid = threadIdx.x;
    const int tx = tid & 15, ty = tid >> 4;
    const int m0 = blockIdx.x * 64, n0 = blockIdx.y * 64;
    float acc[4][4] = {};
    for (int k0 = 0; k0 < K; k0 += 16) {
        #pragma unroll
        for (int p = 0; p < 4; p++) {
            int idx = p * 256 + tid;
            int i = idx >> 4, j = idx & 15;
            As[i][j] = A[(size_t)(m0 + i) * K + k0 + j];
        }
        #pragma unroll
        for (int p = 0; p < 4; p++) {
            int idx = p * 256 + tid;
            int kk = idx >> 6, n = idx & 63;
            Bs[kk][n] = f2b(Bw[(size_t)(k0 + kk) * N + n0 + n]);
        }
        __syncthreads();
        #pragma unroll
        for (int kk = 0; kk < 16; kk++) {
            float a[4], b[4];
            #pragma unroll
            for (int r = 0; r < 4; r++) a[r] = b2f(As[ty * 4 + r][kk]);
            #pragma unroll
            for (int c = 0; c < 4; c++) b[c] = b2f(Bs[kk][tx * 4 + c]);
            #pragma unroll
            for (int r = 0; r < 4; r++)
                #pragma unroll
                for (int c = 0; c < 4; c++) acc[r][c] += a[r] * b[c];
        }
        __syncthreads();
    }
    #pragma unroll
    for (int r = 0; r < 4; r++) {
        const int m = m0 + ty * 4 + r;
        #pragma unroll
        for (int c = 0; c < 4; c++) {
            const int n = n0 + tx * 4 + c;
            float v = acc[r][c];
            if (BIAS) v += bias[n];
            if (RELU) v = fmaxf(v, 0.f);
            if (RES)  v += ldv(res + (size_t)m * N + n);
            stv(Cm + (size_t)m * N + n, v);
        }
    }
}

// ---------------- Fused QKV projection: per-head [C,D] fp32 weights ----------------
// grid: (BT/64, 24). blockIdx.y: 0..7 q-head, 8..15 k-head, 16..23 v-head.
// Output layout: [BT][H*D] with col = h*64+d (bf16 ws).
__global__ __launch_bounds__(256) void qkv_kernel(const bf16* __restrict__ hbuf,
                                                  const float* __restrict__ Wq,
                                                  const float* __restrict__ Wk,
                                                  const float* __restrict__ Wv,
                                                  bf16* __restrict__ qo,
                                                  bf16* __restrict__ ko,
                                                  bf16* __restrict__ vo) {
    __shared__ bf16 As[64][17];
    __shared__ bf16 Bs[16][64];
    const int tid = threadIdx.x;
    const int tx = tid & 15, ty = tid >> 4;
    const int m0 = blockIdx.x * 64;
    const int which = blockIdx.y >> 3, hh = blockIdx.y & 7;
    const float* W = (which == 0 ? Wq : which == 1 ? Wk : Wv) + (size_t)hh * C_ * D_;
    bf16* outp = (which == 0 ? qo : which == 1 ? ko : vo);
    float acc[4][4] = {};
    for (int k0 = 0; k0 < C_; k0 += 16) {
        #pragma unroll
        for (int p = 0; p < 4; p++) {
            int idx = p * 256 + tid;
            int i = idx >> 4, j = idx & 15;
            As[i][j] = hbuf[(size_t)(m0 + i) * C_ + k0 + j];
        }
        #pragma unroll
        for (int p = 0; p < 4; p++) {
            int idx = p * 256 + tid;
            int kk = idx >> 6, n = idx & 63;
            Bs[kk][n] = f2b(W[(size_t)(k0 + kk) * D_ + n]);
        }
        __syncthreads();
        #pragma unroll
        for (int kk = 0; kk < 16; kk++) {
            float a[4], b[4];
            #pragma unroll
            for (int r = 0; r < 4; r++) a[r] = b2f(As[ty * 4 + r][kk]);
            #pragma unroll
            for (int c = 0; c < 4; c++) b[c] = b2f(Bs[kk][tx * 4 + c]);
            #pragma unroll
            for (int r = 0; r < 4; r++)
                #pragma unroll
                for (int c = 0; c < 4; c++) acc[r][c] += a[r] * b[c];
        }
        __syncthreads();
    }
    #pragma unroll
    for (int r = 0; r < 4; r++)
        #pragma unroll
        for (int c = 0; c < 4; c++)
            outp[(size_t)(m0 + ty * 4 + r) * C_ + hh * 64 + tx * 4 + c] = f2b(acc[r][c]);
}

// ---------------- Pass 1: column sums L_s = sum_{t>=s} exp(scale*q_t.k_s) ----------------
// grid: (T/64 key tiles, B*H). 256 threads, 4x4 score microtile.
__global__ __launch_bounds__(256) void colsum_kernel(const bf16* __restrict__ qg,
                                                     const bf16* __restrict__ kg,
                                                     float* __restrict__ L) {
    __shared__ bf16 Qs[64][65];
    __shared__ bf16 Ks[64][65];
    __shared__ float red[16][64];
    const int tid = threadIdx.x;
    const int tx = tid & 15, ty = tid >> 4;
    const int bh = blockIdx.y;
    const int bb = bh >> 3, hh = bh & 7;
    const int s0 = blockIdx.x * 64;
    const bf16* qb = qg + (size_t)bb * T_ * C_ + hh * 64;
    const bf16* kb = kg + (size_t)bb * T_ * C_ + hh * 64;
    #pragma unroll
    for (int p = 0; p < 16; p++) {
        int idx = p * 256 + tid;
        int i = idx >> 6, j = idx & 63;
        Ks[i][j] = kb[(size_t)(s0 + i) * C_ + j];
    }
    float csum[4] = {};
    for (int t0 = s0; t0 < T_; t0 += 64) {
        #pragma unroll
        for (int p = 0; p < 16; p++) {
            int idx = p * 256 + tid;
            int i = idx >> 6, j = idx & 63;
            Qs[i][j] = qb[(size_t)(t0 + i) * C_ + j];
        }
        __syncthreads();
        float sc[4][4] = {};
        for (int d = 0; d < 64; d++) {
            float a[4], b[4];
            #pragma unroll
            for (int r = 0; r < 4; r++) a[r] = b2f(Qs[ty * 4 + r][d]);
            #pragma unroll
            for (int c = 0; c < 4; c++) b[c] = b2f(Ks[tx * 4 + c][d]);
            #pragma unroll
            for (int r = 0; r < 4; r++)
                #pragma unroll
                for (int c = 0; c < 4; c++) sc[r][c] += a[r] * b[c];
        }
        #pragma unroll
        for (int r = 0; r < 4; r++)
            #pragma unroll
            for (int c = 0; c < 4; c++) {
                int t = t0 + ty * 4 + r, s = s0 + tx * 4 + c;
                if (t >= s) csum[c] += __expf(sc[r][c] * SCALE_);
            }
        __syncthreads();
    }
    #pragma unroll
    for (int c = 0; c < 4; c++) red[ty][tx * 4 + c] = csum[c];
    __syncthreads();
    if (tid < 64) {
        float s = 0.f;
        #pragma unroll
        for (int i = 0; i < 16; i++) s += red[i][tid];
        L[(size_t)bh * T_ + s0 + tid] = s;
    }
}

// ---------------- Pass 2: out_t = sum_{s<=t} exp(scale*q_t.k_s) * (v_s / L_s) ----------------
// grid: (T/64 query tiles, B*H).
__global__ __launch_bounds__(256) void attnout_kernel(const bf16* __restrict__ qg,
                                                      const bf16* __restrict__ kg,
                                                      const bf16* __restrict__ vg,
                                                      const float* __restrict__ L,
                                                      bf16* __restrict__ attn) {
    __shared__ bf16 Qs[64][65];
    __shared__ bf16 Ks[64][65];
    __shared__ bf16 Vs[64][68];
    __shared__ float Ps[64][65];
    const int tid = threadIdx.x;
    const int tx = tid & 15, ty = tid >> 4;
    const int bh = blockIdx.y;
    const int bb = bh >> 3, hh = bh & 7;
    const int t0 = blockIdx.x * 64;
    const bf16* qb = qg + (size_t)bb * T_ * C_ + hh * 64;
    const bf16* kb = kg + (size_t)bb * T_ * C_ + hh * 64;
    const bf16* vb = vg + (size_t)bb * T_ * C_ + hh * 64;
    const float* Lb = L + (size_t)bh * T_;
    #pragma unroll
    for (int p = 0; p < 16; p++) {
        int idx = p * 256 + tid;
        int i = idx >> 6, j = idx & 63;
        Qs[i][j] = qb[(size_t)(t0 + i) * C_ + j];
    }
    float acc[4][4] = {};
    for (int s0 = 0; s0 <= t0; s0 += 64) {
        #pragma unroll
        for (int p = 0; p < 16; p++) {
            int idx = p * 256 + tid;
            int i = idx >> 6, j = idx & 63;
            Ks[i][j] = kb[(size_t)(s0 + i) * C_ + j];
            float rl = 1.f / Lb[s0 + i];
            Vs[i][j] = f2b(b2f(vb[(size_t)(s0 + i) * C_ + j]) * rl);
        }
        __syncthreads();
        float sc[4][4] = {};
        for (int d = 0; d < 64; d++) {
            float a[4], b[4];
            #pragma unroll
            for (int r = 0; r < 4; r++) a[r] = b2f(Qs[ty * 4 + r][d]);
            #pragma unroll
            for (int c = 0; c < 4; c++) b[c] = b2f(Ks[tx * 4 + c][d]);
            #pragma unroll
            for (int r = 0; r < 4; r++)
                #pragma unroll
                for (int c = 0; c < 4; c++) sc[r][c] += a[r] * b[c];
        }
        #pragma unroll
        for (int r = 0; r < 4; r++)
            #pragma unroll
            for (int c = 0; c < 4; c++) {
                int t = t0 + ty * 4 + r, s = s0 + tx * 4 + c;
                Ps[ty * 4 + r][tx * 4 + c] = (t >= s) ? __expf(sc[r][c] * SCALE_) : 0.f;
            }
        __syncthreads();
        for (int s = 0; s < 64; s++) {
            float pr[4], vv[4];
            #pragma unroll
            for (int r = 0; r < 4; r++) pr[r] = Ps[ty * 4 + r][s];
            #pragma unroll
            for (int c = 0; c < 4; c++) vv[c] = b2f(Vs[s][tx * 4 + c]);
            #pragma unroll
            for (int r = 0; r < 4; r++)
                #pragma unroll
                for (int c = 0; c < 4; c++) acc[r][c] += pr[r] * vv[c];
        }
        __syncthreads();
    }
    #pragma unroll
    for (int r = 0; r < 4; r++)
        #pragma unroll
        for (int c = 0; c < 4; c++)
            attn[(size_t)(bb * T_ + t0 + ty * 4 + r) * C_ + hh * 64 + tx * 4 + c] =
                f2b(acc[r][c]);
}

extern "C" void kernel_launch(void* const* d_in, const int* in_sizes, int n_in,
                              void* d_out, int out_size, void* d_ws, size_t ws_size,
                              hipStream_t stream) {
    const float* x   = (const float*)d_in[0];
    const float* Wq  = (const float*)d_in[1];
    const float* Wk  = (const float*)d_in[2];
    const float* Wv  = (const float*)d_in[3];
    const float* Wo  = (const float*)d_in[4];
    const float* bo  = (const float*)d_in[5];
    const float* W1  = (const float*)d_in[6];
    const float* b1  = (const float*)d_in[7];
    const float* W2  = (const float*)d_in[8];
    const float* b2  = (const float*)d_in[9];
    const float* g1  = (const float*)d_in[10];
    const float* be1 = (const float*)d_in[11];
    const float* g2  = (const float*)d_in[12];
    const float* be2 = (const float*)d_in[13];
    float* out = (float*)d_out;

    // Workspace carve-up (~92.5 MB, bf16 intermediates, fp32 col-sums).
    char* w = (char*)d_ws;
    auto alloc = [&](size_t bytes) -> void* {
        void* p = (void*)w;
        w += (bytes + 255) & ~(size_t)255;
        return p;
    };
    bf16* hbuf = (bf16*)alloc((size_t)BT_ * C_ * sizeof(bf16));
    bf16* qb   = (bf16*)alloc((size_t)BT_ * C_ * sizeof(bf16));
    bf16* kb   = (bf16*)alloc((size_t)BT_ * C_ * sizeof(bf16));
    bf16* vb   = (bf16*)alloc((size_t)BT_ * C_ * sizeof(bf16));
    bf16* attn = (bf16*)alloc((size_t)BT_ * C_ * sizeof(bf16));
    bf16* x1   = (bf16*)alloc((size_t)BT_ * C_ * sizeof(bf16));
    bf16* h2   = (bf16*)alloc((size_t)BT_ * C_ * sizeof(bf16));
    bf16* ff1  = (bf16*)alloc((size_t)BT_ * C4_ * sizeof(bf16));
    float* L   = (float*)alloc((size_t)B_ * H_ * T_ * sizeof(float));

    // 1. h = LN(x)
    ln_kernel<float><<<BT_, 256, 0, stream>>>(x, g1, be1, hbuf);
    // 2. q,k,v projections (per head)
    qkv_kernel<<<dim3(BT_ / 64, 24), 256, 0, stream>>>(hbuf, Wq, Wk, Wv, qb, kb, vb);
    // 3. column sums of exp(scale*QK^T) under causal mask
    colsum_kernel<<<dim3(T_ / 64, B_ * H_), 256, 0, stream>>>(qb, kb, L);
    // 4. attn out = exp(scale*QK^T) @ (V / L)
    attnout_kernel<<<dim3(T_ / 64, B_ * H_), 256, 0, stream>>>(qb, kb, vb, L, attn);
    // 5. x1 = x + attn @ Wo + bo   (res = fp32 x, out = bf16 ws)
    gemm_kernel<true, true, false, float, bf16><<<dim3(BT_ / 64, C_ / 64), 256, 0, stream>>>(
        attn, Wo, bo, x, x1, BT_, C_, C_);
    // 6. h2 = LN(x1)
    ln_kernel<bf16><<<BT_, 256, 0, stream>>>(x1, g2, be2, h2);
    // 7. ff1 = relu(h2 @ W1 + b1)
    gemm_kernel<true, false, true, float, bf16><<<dim3(BT_ / 64, C4_ / 64), 256, 0, stream>>>(
        h2, W1, b1, (const float*)nullptr, ff1, BT_, C4_, C_);
    // 8. out = x1 + ff1 @ W2 + b2  (res = bf16 x1, out = fp32 d_out)
    gemm_kernel<true, true, false, bf16, float><<<dim3(BT_ / 64, C_ / 64), 256, 0, stream>>>(
        ff1, W2, b2, x1, out, BT_, C_, C4_);
}

// Round 3
// 364.723 us; speedup vs baseline: 10.0209x; 10.0209x over previous
//
#include <hip/hip_runtime.h>
#include <hip/hip_bf16.h>

// Block_4776003633552: transformer block, B=4 T=2048 C=512 H=8 D=64. fp32 I/O.
// Reference quirks: scale = C^-0.5; softmax over QUERY axis (axis=-2) =>
//   out_t = sum_{s<=t} exp(sc*q_t.k_s) * v_s / L_s,  L_s = sum_{t>=s} exp(sc*q_t.k_s).
// Round 3: full MFMA (v_mfma_f32_16x16x32_bf16) for QKV/Wo/W1/W2 GEMMs and both
// attention passes. Weights pre-transposed+converted to bf16 [N][K] in ws.
// V written transposed (vt[b][h*64+d][t]) by the QKV GEMM epilogue so PV's
// B-operand is k-contiguous in LDS. 1/L folded into P (colsum stores recips).

typedef __hip_bfloat16 bf16;
typedef __bf16 b8v __attribute__((ext_vector_type(8)));   // MFMA A/B fragment (8 bf16)
typedef float  f32x4 __attribute__((ext_vector_type(4))); // MFMA C/D fragment
typedef short  s8v  __attribute__((ext_vector_type(8)));  // 16B bf16 copy chunk

#define B_   4
#define T_   2048
#define C_   512
#define H_   8
#define D_   64
#define BT_  (B_ * T_)
#define C4_  (4 * C_)
#define EPS_ 1e-5f
#define SCALE_ 0.04419417382415922f  // 1/sqrt(512)

#define MFMA16(a, b, c) __builtin_amdgcn_mfma_f32_16x16x32_bf16(a, b, c, 0, 0, 0)

static __device__ __forceinline__ float b2f(bf16 x) { return __bfloat162float(x); }
static __device__ __forceinline__ bf16  f2b(float x) { return __float2bfloat16(x); }
static __device__ __forceinline__ short f2bs(float x) {
    bf16 h = f2b(x);
    return __builtin_bit_cast(short, h);
}

// ---------------- LayerNorm over C=512, one block per row ----------------
static __device__ __forceinline__ float ldv(const float* p) { return *p; }
static __device__ __forceinline__ float ldv(const bf16* p)  { return b2f(*p); }

template <typename TIN>
__global__ __launch_bounds__(256) void ln_kernel(const TIN* __restrict__ x,
                                                 const float* __restrict__ g,
                                                 const float* __restrict__ be,
                                                 bf16* __restrict__ out) {
    const int row = blockIdx.x;
    const int tid = threadIdx.x;
    const TIN* xr = x + (size_t)row * C_;
    float v0 = ldv(xr + tid * 2);
    float v1 = ldv(xr + tid * 2 + 1);
    float s = v0 + v1;
    float sq = v0 * v0 + v1 * v1;
    #pragma unroll
    for (int o = 32; o > 0; o >>= 1) {
        s += __shfl_down(s, o);
        sq += __shfl_down(sq, o);
    }
    __shared__ float ws[8], wsq[8];
    const int wid = tid >> 6, lane = tid & 63;
    if (lane == 0) { ws[wid] = s; wsq[wid] = sq; }
    __syncthreads();
    if (tid == 0) {
        float ts = 0.f, tq = 0.f;
        #pragma unroll
        for (int i = 0; i < 4; i++) { ts += ws[i]; tq += wsq[i]; }
        float mu = ts * (1.f / C_);
        float var = tq * (1.f / C_) - mu * mu;
        ws[4] = mu;
        wsq[4] = rsqrtf(var + EPS_);
    }
    __syncthreads();
    const float mu = ws[4], rstd = wsq[4];
    bf16* orow = out + (size_t)row * C_;
    orow[tid * 2]     = f2b((v0 - mu) * rstd * g[tid * 2]     + be[tid * 2]);
    orow[tid * 2 + 1] = f2b((v1 - mu) * rstd * g[tid * 2 + 1] + be[tid * 2 + 1]);
}

// ---------------- Transpose + fp32->bf16 convert: dst[n][k] = src[k][n] ----------------
__global__ __launch_bounds__(256) void transpose_cvt(const float* __restrict__ src,
                                                     bf16* __restrict__ dst,
                                                     int R, int Cc) {
    __shared__ float Ts[64][65];
    const int tid = threadIdx.x;
    const int r0 = blockIdx.x * 64, c0 = blockIdx.y * 64;
    #pragma unroll
    for (int p = 0; p < 16; p++) {
        int idx = p * 256 + tid, i = idx >> 6, j = idx & 63;
        Ts[i][j] = src[(size_t)(r0 + i) * Cc + c0 + j];
    }
    __syncthreads();
    #pragma unroll
    for (int p = 0; p < 16; p++) {
        int idx = p * 256 + tid, j = idx >> 6, i = idx & 63;
        dst[(size_t)(c0 + j) * R + r0 + i] = f2b(Ts[i][j]);
    }
}

// per-head weight [H][C][D] -> dst rows (h*64+d), cols c: dst[(h*64+d)*512 + c]
__global__ __launch_bounds__(256) void qkv_transpose(const float* __restrict__ src,
                                                     bf16* __restrict__ dst) {
    __shared__ float Ts[64][65];
    const int tid = threadIdx.x;
    const int c0 = blockIdx.x * 64, hh = blockIdx.y;
    const float* s = src + (size_t)hh * C_ * D_;
    #pragma unroll
    for (int p = 0; p < 16; p++) {
        int idx = p * 256 + tid, i = idx >> 6, j = idx & 63;
        Ts[i][j] = s[(size_t)(c0 + i) * D_ + j];
    }
    __syncthreads();
    #pragma unroll
    for (int p = 0; p < 16; p++) {
        int idx = p * 256 + tid, j = idx >> 6, i = idx & 63;
        dst[(size_t)(hh * 64 + j) * C_ + c0 + i] = f2b(Ts[i][j]);
    }
}

// ---------------- MFMA GEMM: C[M,N] = A[M,K] @ Bt[N,K]^T ----------------
// 128x128 tile, BK=32, 256 threads = 4 waves (2x2 of 64x64), 4x4 mfma tiles/wave.
// global_load_lds width-16 staging (m97 structure).
// MODE 1: +bias +relu -> bf16.  MODE 2: +bias +fp32 res -> bf16.
// MODE 3: +bias +bf16 res -> fp32.  MODE 4: QKV split (q,k -> qkvb [m][1024]; v -> vt).
template <int MODE>
__global__ __launch_bounds__(256) void mfma_gemm(const bf16* __restrict__ A,
                                                 const bf16* __restrict__ Bt,
                                                 const float* __restrict__ bias,
                                                 const float* __restrict__ resf,
                                                 const bf16* __restrict__ resb,
                                                 bf16* __restrict__ outb,
                                                 float* __restrict__ outf,
                                                 bf16* __restrict__ qkvb,
                                                 bf16* __restrict__ vt,
                                                 int M, int N, int K) {
    __shared__ short As[128 * 32];
    __shared__ short Bs[128 * 32];
    const int tid = threadIdx.x;
    const int lane = tid & 63, wv = tid >> 6;
    const int wm = wv >> 1, wn = wv & 1;
    const int m0 = blockIdx.x * 128, n0 = blockIdx.y * 128;
    const int lrow = lane >> 2, lk = (lane & 3) * 8;
    const int lm = lane & 15, quad = lane >> 4;

    f32x4 acc[4][4];
    #pragma unroll
    for (int r = 0; r < 4; r++)
        #pragma unroll
        for (int c = 0; c < 4; c++) {
            f32x4 z = {0.f, 0.f, 0.f, 0.f};
            acc[r][c] = z;
        }

    for (int k0 = 0; k0 < K; k0 += 32) {
        #pragma unroll
        for (int cc = 0; cc < 2; cc++) {
            const int row = cc * 64 + wv * 16 + lrow;
            const bf16* ga = A + (size_t)(m0 + row) * K + k0 + lk;
            __builtin_amdgcn_global_load_lds(
                (const __attribute__((address_space(1))) void*)ga,
                (__attribute__((address_space(3))) void*)&As[(cc * 64 + wv * 16) * 32],
                16, 0, 0);
            const bf16* gb = Bt + (size_t)(n0 + row) * K + k0 + lk;
            __builtin_amdgcn_global_load_lds(
                (const __attribute__((address_space(1))) void*)gb,
                (__attribute__((address_space(3))) void*)&Bs[(cc * 64 + wv * 16) * 32],
                16, 0, 0);
        }
        __syncthreads();
        b8v af[4], bfr[4];
        #pragma unroll
        for (int r = 0; r < 4; r++)
            af[r] = *(const b8v*)&As[(wm * 64 + r * 16 + lm) * 32 + quad * 8];
        #pragma unroll
        for (int c = 0; c < 4; c++)
            bfr[c] = *(const b8v*)&Bs[(wn * 64 + c * 16 + lm) * 32 + quad * 8];
        #pragma unroll
        for (int r = 0; r < 4; r++)
            #pragma unroll
            for (int c = 0; c < 4; c++)
                acc[r][c] = MFMA16(af[r], bfr[c], acc[r][c]);
        __syncthreads();
    }

    #pragma unroll
    for (int r = 0; r < 4; r++) {
        const int mbase = m0 + wm * 64 + r * 16 + quad * 4;
        #pragma unroll
        for (int c = 0; c < 4; c++) {
            const int n = n0 + wn * 64 + c * 16 + lm;
            #pragma unroll
            for (int reg = 0; reg < 4; reg++) {
                const int m = mbase + reg;
                float v = acc[r][c][reg];
                if (MODE == 1) {
                    v += bias[n];
                    v = fmaxf(v, 0.f);
                    outb[(size_t)m * N + n] = f2b(v);
                } else if (MODE == 2) {
                    v += bias[n] + resf[(size_t)m * N + n];
                    outb[(size_t)m * N + n] = f2b(v);
                } else if (MODE == 3) {
                    v += bias[n] + b2f(resb[(size_t)m * N + n]);
                    outf[(size_t)m * N + n] = v;
                } else {  // MODE 4: QKV
                    if (n < 1024) {
                        qkvb[(size_t)m * 1024 + n] = f2b(v);
                    } else {
                        vt[((size_t)(m >> 11) * 512 + (n - 1024)) * T_ + (m & (T_ - 1))] =
                            f2b(v);
                    }
                }
            }
        }
    }
}

// ---------------- Pass 1: Lr[s] = 1 / sum_{t>=s} exp(sc*q_t.k_s) ----------------
// grid (T/64, B*H), 256 threads = 4 waves; wave w handles query rows w*16..+16.
__global__ __launch_bounds__(256) void colsum_mfma(const bf16* __restrict__ qkv,
                                                   float* __restrict__ Lr) {
    __shared__ short Ks[64 * 72];
    __shared__ short Qs[64 * 72];
    __shared__ float red[4][64];
    const int tid = threadIdx.x, lane = tid & 63, wv = tid >> 6;
    const int lm = lane & 15, quad = lane >> 4;
    const int s0 = blockIdx.x * 64;
    const int bh = blockIdx.y, bb = bh >> 3, hh = bh & 7;
    const bf16* qbase = qkv + (size_t)bb * T_ * 1024 + hh * 64;
    const bf16* kbase = qbase + 512;
    #pragma unroll
    for (int cc = 0; cc < 2; cc++) {
        int idx = cc * 256 + tid, s = idx >> 3, dch = idx & 7;
        *(s8v*)&Ks[s * 72 + dch * 8] =
            *(const s8v*)(kbase + (size_t)(s0 + s) * 1024 + dch * 8);
    }
    float csum[4] = {0.f, 0.f, 0.f, 0.f};
    for (int t0 = s0; t0 < T_; t0 += 64) {
        #pragma unroll
        for (int cc = 0; cc < 2; cc++) {
            int idx = cc * 256 + tid, s = idx >> 3, dch = idx & 7;
            *(s8v*)&Qs[s * 72 + dch * 8] =
                *(const s8v*)(qbase + (size_t)(t0 + s) * 1024 + dch * 8);
        }
        __syncthreads();
        b8v aq0 = *(const b8v*)&Qs[(wv * 16 + lm) * 72 + quad * 8];
        b8v aq1 = *(const b8v*)&Qs[(wv * 16 + lm) * 72 + 32 + quad * 8];
        #pragma unroll
        for (int c = 0; c < 4; c++) {
            b8v bk0 = *(const b8v*)&Ks[(c * 16 + lm) * 72 + quad * 8];
            b8v bk1 = *(const b8v*)&Ks[(c * 16 + lm) * 72 + 32 + quad * 8];
            f32x4 S = {0.f, 0.f, 0.f, 0.f};
            S = MFMA16(aq0, bk0, S);
            S = MFMA16(aq1, bk1, S);
            const int s = s0 + c * 16 + lm;
            #pragma unroll
            for (int reg = 0; reg < 4; reg++) {
                int t = t0 + wv * 16 + quad * 4 + reg;
                if (t >= s) csum[c] += __expf(S[reg] * SCALE_);
            }
        }
        __syncthreads();
    }
    #pragma unroll
    for (int c = 0; c < 4; c++) {
        float v = csum[c];
        v += __shfl_xor(v, 16);
        v += __shfl_xor(v, 32);
        if (lane < 16) red[wv][c * 16 + lane] = v;
    }
    __syncthreads();
    if (tid < 64) {
        float s = red[0][tid] + red[1][tid] + red[2][tid] + red[3][tid];
        Lr[(size_t)bh * T_ + s0 + tid] = 1.0f / s;
    }
}

// ---------------- Pass 2: out_t = sum_{s<=t} (exp(sc*q_t.k_s)/L_s) * v_s ----------------
// grid (T/64, B*H). P round-trips through LDS (C-layout -> A-layout), 1/L folded into P.
__global__ __launch_bounds__(256) void attnout_mfma(const bf16* __restrict__ qkv,
                                                    const bf16* __restrict__ vt,
                                                    const float* __restrict__ Lr,
                                                    bf16* __restrict__ attn) {
    __shared__ short Qs[64 * 72];
    __shared__ short Ks[64 * 72];
    __shared__ short Vt[64 * 72];
    __shared__ short Ps[64 * 72];
    const int tid = threadIdx.x, lane = tid & 63, wv = tid >> 6;
    const int lm = lane & 15, quad = lane >> 4;
    const int t0 = blockIdx.x * 64;
    const int bh = blockIdx.y, bb = bh >> 3, hh = bh & 7;
    const bf16* qbase = qkv + (size_t)bb * T_ * 1024 + hh * 64;
    const bf16* kbase = qbase + 512;
    const bf16* vtb = vt + ((size_t)bb * 512 + hh * 64) * T_;
    const float* Lrb = Lr + (size_t)bh * T_;
    #pragma unroll
    for (int cc = 0; cc < 2; cc++) {
        int idx = cc * 256 + tid, s = idx >> 3, dch = idx & 7;
        *(s8v*)&Qs[s * 72 + dch * 8] =
            *(const s8v*)(qbase + (size_t)(t0 + s) * 1024 + dch * 8);
    }
    f32x4 o[4];
    #pragma unroll
    for (int c = 0; c < 4; c++) {
        f32x4 z = {0.f, 0.f, 0.f, 0.f};
        o[c] = z;
    }
    for (int s0 = 0; s0 <= t0; s0 += 64) {
        #pragma unroll
        for (int cc = 0; cc < 2; cc++) {
            int idx = cc * 256 + tid, s = idx >> 3, dch = idx & 7;
            *(s8v*)&Ks[s * 72 + dch * 8] =
                *(const s8v*)(kbase + (size_t)(s0 + s) * 1024 + dch * 8);
            // Vt row d = s index here; 8 s-elements per chunk
            *(s8v*)&Vt[s * 72 + dch * 8] =
                *(const s8v*)(vtb + (size_t)s * T_ + s0 + dch * 8);
        }
        __syncthreads();
        b8v aq0 = *(const b8v*)&Qs[(wv * 16 + lm) * 72 + quad * 8];
        b8v aq1 = *(const b8v*)&Qs[(wv * 16 + lm) * 72 + 32 + quad * 8];
        #pragma unroll
        for (int c = 0; c < 4; c++) {
            b8v bk0 = *(const b8v*)&Ks[(c * 16 + lm) * 72 + quad * 8];
            b8v bk1 = *(const b8v*)&Ks[(c * 16 + lm) * 72 + 32 + quad * 8];
            f32x4 S = {0.f, 0.f, 0.f, 0.f};
            S = MFMA16(aq0, bk0, S);
            S = MFMA16(aq1, bk1, S);
            const int s = s0 + c * 16 + lm;
            const float rl = Lrb[s];
            #pragma unroll
            for (int reg = 0; reg < 4; reg++) {
                int t = t0 + wv * 16 + quad * 4 + reg;
                float e = (t >= s) ? __expf(S[reg] * SCALE_) * rl : 0.f;
                Ps[(wv * 16 + quad * 4 + reg) * 72 + c * 16 + lm] = f2bs(e);
            }
        }
        __syncthreads();
        b8v ap0 = *(const b8v*)&Ps[(wv * 16 + lm) * 72 + quad * 8];
        b8v ap1 = *(const b8v*)&Ps[(wv * 16 + lm) * 72 + 32 + quad * 8];
        #pragma unroll
        for (int c = 0; c < 4; c++) {
            b8v bv0 = *(const b8v*)&Vt[(c * 16 + lm) * 72 + quad * 8];
            b8v bv1 = *(const b8v*)&Vt[(c * 16 + lm) * 72 + 32 + quad * 8];
            o[c] = MFMA16(ap0, bv0, o[c]);
            o[c] = MFMA16(ap1, bv1, o[c]);
        }
        __syncthreads();
    }
    #pragma unroll
    for (int c = 0; c < 4; c++)
        #pragma unroll
        for (int reg = 0; reg < 4; reg++)
            attn[(size_t)(bb * T_ + t0 + wv * 16 + quad * 4 + reg) * C_ + hh * 64 +
                 c * 16 + lm] = f2b(o[c][reg]);
}

extern "C" void kernel_launch(void* const* d_in, const int* in_sizes, int n_in,
                              void* d_out, int out_size, void* d_ws, size_t ws_size,
                              hipStream_t stream) {
    const float* x   = (const float*)d_in[0];
    const float* Wq  = (const float*)d_in[1];
    const float* Wk  = (const float*)d_in[2];
    const float* Wv  = (const float*)d_in[3];
    const float* Wo  = (const float*)d_in[4];
    const float* bo  = (const float*)d_in[5];
    const float* W1  = (const float*)d_in[6];
    const float* b1  = (const float*)d_in[7];
    const float* W2  = (const float*)d_in[8];
    const float* b2  = (const float*)d_in[9];
    const float* g1  = (const float*)d_in[10];
    const float* be1 = (const float*)d_in[11];
    const float* g2  = (const float*)d_in[12];
    const float* be2 = (const float*)d_in[13];
    float* out = (float*)d_out;

    // Workspace (~62 MB). Region A (32 MB) is time-multiplexed:
    //   [qkvb 16MB | attn 8MB | hbuf 8MB]  then reused whole as ff1 (32MB).
    // Lifetimes: hbuf LN1->QKV; qkvb QKV->attnout; attn attnout->Wo; ff1 W1->W2.
    char* w = (char*)d_ws;
    auto alloc = [&](size_t bytes) -> void* {
        void* p = (void*)w;
        w += (bytes + 255) & ~(size_t)255;
        return p;
    };
    bf16* regionA = (bf16*)alloc((size_t)BT_ * 2048 * sizeof(bf16));  // 32MB
    bf16* qkvb = regionA;                                // [BT][1024] (q|k)
    bf16* attn = regionA + (size_t)BT_ * 1024;           // [BT][512]
    bf16* hbuf = regionA + (size_t)BT_ * 1536;           // [BT][512]
    bf16* ff1  = regionA;                                // [BT][2048]
    bf16* x1     = (bf16*)alloc((size_t)BT_ * C_ * sizeof(bf16));
    bf16* h2     = (bf16*)alloc((size_t)BT_ * C_ * sizeof(bf16));
    bf16* vt     = (bf16*)alloc((size_t)B_ * 512 * T_ * sizeof(bf16));   // [B][H*D][T]
    bf16* WqkvT  = (bf16*)alloc((size_t)1536 * C_ * sizeof(bf16));       // [1536][512]
    bf16* WoT    = (bf16*)alloc((size_t)C_ * C_ * sizeof(bf16));
    bf16* W1T    = (bf16*)alloc((size_t)C4_ * C_ * sizeof(bf16));        // [2048][512]
    bf16* W2T    = (bf16*)alloc((size_t)C_ * C4_ * sizeof(bf16));        // [512][2048]
    float* Lr    = (float*)alloc((size_t)B_ * H_ * T_ * sizeof(float));

    // Weight transposes (fp32 -> bf16 [N][K])
    qkv_transpose<<<dim3(8, 8), 256, 0, stream>>>(Wq, WqkvT);
    qkv_transpose<<<dim3(8, 8), 256, 0, stream>>>(Wk, WqkvT + (size_t)512 * C_);
    qkv_transpose<<<dim3(8, 8), 256, 0, stream>>>(Wv, WqkvT + (size_t)1024 * C_);
    transpose_cvt<<<dim3(8, 8), 256, 0, stream>>>(Wo, WoT, 512, 512);
    transpose_cvt<<<dim3(8, 32), 256, 0, stream>>>(W1, W1T, 512, 2048);
    transpose_cvt<<<dim3(32, 8), 256, 0, stream>>>(W2, W2T, 2048, 512);

    // 1. h = LN(x)
    ln_kernel<float><<<BT_, 256, 0, stream>>>(x, g1, be1, hbuf);
    // 2. QKV GEMM: [8192,1536,512]; q,k -> qkvb, v -> vt (transposed)
    mfma_gemm<4><<<dim3(BT_ / 128, 1536 / 128), 256, 0, stream>>>(
        hbuf, WqkvT, nullptr, nullptr, nullptr, nullptr, nullptr, qkvb, vt,
        BT_, 1536, C_);
    // 3. column-sum reciprocals
    colsum_mfma<<<dim3(T_ / 64, B_ * H_), 256, 0, stream>>>(qkvb, Lr);
    // 4. attention output
    attnout_mfma<<<dim3(T_ / 64, B_ * H_), 256, 0, stream>>>(qkvb, vt, Lr, attn);
    // 5. x1 = x + attn @ Wo + bo
    mfma_gemm<2><<<dim3(BT_ / 128, C_ / 128), 256, 0, stream>>>(
        attn, WoT, bo, x, nullptr, x1, nullptr, nullptr, nullptr, BT_, C_, C_);
    // 6. h2 = LN(x1)
    ln_kernel<bf16><<<BT_, 256, 0, stream>>>(x1, g2, be2, h2);
    // 7. ff1 = relu(h2 @ W1 + b1)
    mfma_gemm<1><<<dim3(BT_ / 128, C4_ / 128), 256, 0, stream>>>(
        h2, W1T, b1, nullptr, nullptr, ff1, nullptr, nullptr, nullptr, BT_, C4_, C_);
    // 8. out = x1 + ff1 @ W2 + b2
    mfma_gemm<3><<<dim3(BT_ / 128, C_ / 128), 256, 0, stream>>>(
        ff1, W2T, b2, nullptr, x1, nullptr, out, nullptr, nullptr, BT_, C_, C4_);
}

// Round 4
// 337.451 us; speedup vs baseline: 10.8308x; 1.0808x over previous
//
#include <hip/hip_runtime.h>
#include <hip/hip_bf16.h>

// Block_4776003633552: transformer block, B=4 T=2048 C=512 H=8 D=64. fp32 I/O.
// Reference quirks: scale = C^-0.5; softmax over QUERY axis (axis=-2) =>
//   out_t = sum_{s<=t} exp(sc*q_t.k_s) * v_s / L_s,  L_s = sum_{t>=s} exp(sc*q_t.k_s).
// Round 4: attention restructured — strip-paired blocks (perfect balance, 256 blocks),
// 512 threads, 128-row Q strips, S^T-MFMA so P packs into ds_write_b64, 1/L folded
// into V at staging. GEMMs unchanged (m97-style 128x128 global_load_lds).

typedef __hip_bfloat16 bf16;
typedef __bf16 b8v __attribute__((ext_vector_type(8)));   // MFMA A/B fragment (8 bf16)
typedef float  f32x4 __attribute__((ext_vector_type(4))); // MFMA C/D fragment
typedef short  s8v  __attribute__((ext_vector_type(8)));  // 16B bf16 copy chunk
typedef short  s4v  __attribute__((ext_vector_type(4)));  // 8B packed P write

#define B_   4
#define T_   2048
#define C_   512
#define H_   8
#define D_   64
#define BT_  (B_ * T_)
#define C4_  (4 * C_)
#define EPS_ 1e-5f
#define SCALE_ 0.04419417382415922f  // 1/sqrt(512)

#define MFMA16(a, b, c) __builtin_amdgcn_mfma_f32_16x16x32_bf16(a, b, c, 0, 0, 0)

static __device__ __forceinline__ float b2f(bf16 x) { return __bfloat162float(x); }
static __device__ __forceinline__ bf16  f2b(float x) { return __float2bfloat16(x); }
static __device__ __forceinline__ short f2bs(float x) {
    bf16 h = f2b(x);
    return __builtin_bit_cast(short, h);
}
static __device__ __forceinline__ float s2f(short x) {
    return b2f(__builtin_bit_cast(bf16, x));
}

// ---------------- LayerNorm over C=512, one block per row ----------------
static __device__ __forceinline__ float ldv(const float* p) { return *p; }
static __device__ __forceinline__ float ldv(const bf16* p)  { return b2f(*p); }

template <typename TIN>
__global__ __launch_bounds__(256) void ln_kernel(const TIN* __restrict__ x,
                                                 const float* __restrict__ g,
                                                 const float* __restrict__ be,
                                                 bf16* __restrict__ out) {
    const int row = blockIdx.x;
    const int tid = threadIdx.x;
    const TIN* xr = x + (size_t)row * C_;
    float v0 = ldv(xr + tid * 2);
    float v1 = ldv(xr + tid * 2 + 1);
    float s = v0 + v1;
    float sq = v0 * v0 + v1 * v1;
    #pragma unroll
    for (int o = 32; o > 0; o >>= 1) {
        s += __shfl_down(s, o);
        sq += __shfl_down(sq, o);
    }
    __shared__ float ws[8], wsq[8];
    const int wid = tid >> 6, lane = tid & 63;
    if (lane == 0) { ws[wid] = s; wsq[wid] = sq; }
    __syncthreads();
    if (tid == 0) {
        float ts = 0.f, tq = 0.f;
        #pragma unroll
        for (int i = 0; i < 4; i++) { ts += ws[i]; tq += wsq[i]; }
        float mu = ts * (1.f / C_);
        float var = tq * (1.f / C_) - mu * mu;
        ws[4] = mu;
        wsq[4] = rsqrtf(var + EPS_);
    }
    __syncthreads();
    const float mu = ws[4], rstd = wsq[4];
    bf16* orow = out + (size_t)row * C_;
    orow[tid * 2]     = f2b((v0 - mu) * rstd * g[tid * 2]     + be[tid * 2]);
    orow[tid * 2 + 1] = f2b((v1 - mu) * rstd * g[tid * 2 + 1] + be[tid * 2 + 1]);
}

// ---------------- Transpose + fp32->bf16 convert: dst[n][k] = src[k][n] ----------------
__global__ __launch_bounds__(256) void transpose_cvt(const float* __restrict__ src,
                                                     bf16* __restrict__ dst,
                                                     int R, int Cc) {
    __shared__ float Ts[64][65];
    const int tid = threadIdx.x;
    const int r0 = blockIdx.x * 64, c0 = blockIdx.y * 64;
    #pragma unroll
    for (int p = 0; p < 16; p++) {
        int idx = p * 256 + tid, i = idx >> 6, j = idx & 63;
        Ts[i][j] = src[(size_t)(r0 + i) * Cc + c0 + j];
    }
    __syncthreads();
    #pragma unroll
    for (int p = 0; p < 16; p++) {
        int idx = p * 256 + tid, j = idx >> 6, i = idx & 63;
        dst[(size_t)(c0 + j) * R + r0 + i] = f2b(Ts[i][j]);
    }
}

// per-head weight [H][C][D] -> dst rows (h*64+d), cols c: dst[(h*64+d)*512 + c]
__global__ __launch_bounds__(256) void qkv_transpose(const float* __restrict__ src,
                                                     bf16* __restrict__ dst) {
    __shared__ float Ts[64][65];
    const int tid = threadIdx.x;
    const int c0 = blockIdx.x * 64, hh = blockIdx.y;
    const float* s = src + (size_t)hh * C_ * D_;
    #pragma unroll
    for (int p = 0; p < 16; p++) {
        int idx = p * 256 + tid, i = idx >> 6, j = idx & 63;
        Ts[i][j] = s[(size_t)(c0 + i) * D_ + j];
    }
    __syncthreads();
    #pragma unroll
    for (int p = 0; p < 16; p++) {
        int idx = p * 256 + tid, j = idx >> 6, i = idx & 63;
        dst[(size_t)(hh * 64 + j) * C_ + c0 + i] = f2b(Ts[i][j]);
    }
}

// ---------------- MFMA GEMM: C[M,N] = A[M,K] @ Bt[N,K]^T ----------------
// 128x128 tile, BK=32, 256 threads = 4 waves (2x2 of 64x64), 4x4 mfma tiles/wave.
// MODE 1: +bias +relu -> bf16.  MODE 2: +bias +fp32 res -> bf16.
// MODE 3: +bias +bf16 res -> fp32.  MODE 4: QKV split (q,k -> qkvb; v -> vt).
template <int MODE>
__global__ __launch_bounds__(256) void mfma_gemm(const bf16* __restrict__ A,
                                                 const bf16* __restrict__ Bt,
                                                 const float* __restrict__ bias,
                                                 const float* __restrict__ resf,
                                                 const bf16* __restrict__ resb,
                                                 bf16* __restrict__ outb,
                                                 float* __restrict__ outf,
                                                 bf16* __restrict__ qkvb,
                                                 bf16* __restrict__ vt,
                                                 int M, int N, int K) {
    __shared__ short As[128 * 32];
    __shared__ short Bs[128 * 32];
    const int tid = threadIdx.x;
    const int lane = tid & 63, wv = tid >> 6;
    const int wm = wv >> 1, wn = wv & 1;
    const int m0 = blockIdx.x * 128, n0 = blockIdx.y * 128;
    const int lrow = lane >> 2, lk = (lane & 3) * 8;
    const int lm = lane & 15, quad = lane >> 4;

    f32x4 acc[4][4];
    #pragma unroll
    for (int r = 0; r < 4; r++)
        #pragma unroll
        for (int c = 0; c < 4; c++) {
            f32x4 z = {0.f, 0.f, 0.f, 0.f};
            acc[r][c] = z;
        }

    for (int k0 = 0; k0 < K; k0 += 32) {
        #pragma unroll
        for (int cc = 0; cc < 2; cc++) {
            const int row = cc * 64 + wv * 16 + lrow;
            const bf16* ga = A + (size_t)(m0 + row) * K + k0 + lk;
            __builtin_amdgcn_global_load_lds(
                (const __attribute__((address_space(1))) void*)ga,
                (__attribute__((address_space(3))) void*)&As[(cc * 64 + wv * 16) * 32],
                16, 0, 0);
            const bf16* gb = Bt + (size_t)(n0 + row) * K + k0 + lk;
            __builtin_amdgcn_global_load_lds(
                (const __attribute__((address_space(1))) void*)gb,
                (__attribute__((address_space(3))) void*)&Bs[(cc * 64 + wv * 16) * 32],
                16, 0, 0);
        }
        __syncthreads();
        b8v af[4], bfr[4];
        #pragma unroll
        for (int r = 0; r < 4; r++)
            af[r] = *(const b8v*)&As[(wm * 64 + r * 16 + lm) * 32 + quad * 8];
        #pragma unroll
        for (int c = 0; c < 4; c++)
            bfr[c] = *(const b8v*)&Bs[(wn * 64 + c * 16 + lm) * 32 + quad * 8];
        #pragma unroll
        for (int r = 0; r < 4; r++)
            #pragma unroll
            for (int c = 0; c < 4; c++)
                acc[r][c] = MFMA16(af[r], bfr[c], acc[r][c]);
        __syncthreads();
    }

    #pragma unroll
    for (int r = 0; r < 4; r++) {
        const int mbase = m0 + wm * 64 + r * 16 + quad * 4;
        #pragma unroll
        for (int c = 0; c < 4; c++) {
            const int n = n0 + wn * 64 + c * 16 + lm;
            #pragma unroll
            for (int reg = 0; reg < 4; reg++) {
                const int m = mbase + reg;
                float v = acc[r][c][reg];
                if (MODE == 1) {
                    v += bias[n];
                    v = fmaxf(v, 0.f);
                    outb[(size_t)m * N + n] = f2b(v);
                } else if (MODE == 2) {
                    v += bias[n] + resf[(size_t)m * N + n];
                    outb[(size_t)m * N + n] = f2b(v);
                } else if (MODE == 3) {
                    v += bias[n] + b2f(resb[(size_t)m * N + n]);
                    outf[(size_t)m * N + n] = v;
                } else {  // MODE 4: QKV
                    if (n < 1024) {
                        qkvb[(size_t)m * 1024 + n] = f2b(v);
                    } else {
                        vt[((size_t)(m >> 11) * 512 + (n - 1024)) * T_ + (m & (T_ - 1))] =
                            f2b(v);
                    }
                }
            }
        }
    }
}

// ---------------- Pass 1: Lr[s] = 1 / sum_{t>=s} exp(sc*q_t.k_s) ----------------
// Strip-paired: block x in [0,8) handles key strips {x, 15-x} (128 keys each) ->
// every block does exactly 17 Q-tile (128-row) iterations. 512 threads = 8 waves.
__global__ __launch_bounds__(512) void colsum_mfma(const bf16* __restrict__ qkv,
                                                   float* __restrict__ Lr) {
    __shared__ short Ks[128 * 72];
    __shared__ short Qs[128 * 72];
    __shared__ float red[8][128];
    const int tid = threadIdx.x, lane = tid & 63, wv = tid >> 6;
    const int lm = lane & 15, quad = lane >> 4;
    const int bh = blockIdx.y, bb = bh >> 3, hh = bh & 7;
    const bf16* qbase = qkv + (size_t)bb * T_ * 1024 + hh * 64;
    const bf16* kbase = qbase + 512;
    for (int half = 0; half < 2; half++) {
        const int strip = half ? 15 - blockIdx.x : blockIdx.x;
        const int s0 = strip * 128;
        #pragma unroll
        for (int cc = 0; cc < 2; cc++) {
            int idx = cc * 512 + tid, r = idx >> 3, ch = idx & 7;
            *(s8v*)&Ks[r * 72 + ch * 8] =
                *(const s8v*)(kbase + (size_t)(s0 + r) * 1024 + ch * 8);
        }
        float csum[8] = {};
        for (int t0 = s0; t0 < T_; t0 += 128) {
            #pragma unroll
            for (int cc = 0; cc < 2; cc++) {
                int idx = cc * 512 + tid, r = idx >> 3, ch = idx & 7;
                *(s8v*)&Qs[r * 72 + ch * 8] =
                    *(const s8v*)(qbase + (size_t)(t0 + r) * 1024 + ch * 8);
            }
            __syncthreads();
            b8v aq0 = *(const b8v*)&Qs[(wv * 16 + lm) * 72 + quad * 8];
            b8v aq1 = *(const b8v*)&Qs[(wv * 16 + lm) * 72 + 32 + quad * 8];
            #pragma unroll
            for (int c = 0; c < 8; c++) {
                b8v bk0 = *(const b8v*)&Ks[(c * 16 + lm) * 72 + quad * 8];
                b8v bk1 = *(const b8v*)&Ks[(c * 16 + lm) * 72 + 32 + quad * 8];
                f32x4 S = {0.f, 0.f, 0.f, 0.f};
                S = MFMA16(aq0, bk0, S);
                S = MFMA16(aq1, bk1, S);
                const int s = s0 + c * 16 + lm;
                #pragma unroll
                for (int reg = 0; reg < 4; reg++) {
                    int t = t0 + wv * 16 + quad * 4 + reg;
                    if (t >= s) csum[c] += __expf(S[reg] * SCALE_);
                }
            }
            __syncthreads();
        }
        #pragma unroll
        for (int c = 0; c < 8; c++) {
            float v = csum[c];
            v += __shfl_xor(v, 16);
            v += __shfl_xor(v, 32);
            if (lane < 16) red[wv][c * 16 + lane] = v;
        }
        __syncthreads();
        if (tid < 128) {
            float s = 0.f;
            #pragma unroll
            for (int i = 0; i < 8; i++) s += red[i][tid];
            Lr[(size_t)bh * T_ + s0 + tid] = 1.0f / s;
        }
        __syncthreads();
    }
}

// ---------------- Pass 2: out_t = sum_{s<=t} exp(sc*q_t.k_s) * (v_s * Lr_s) ----------------
// Strip-paired: block x handles query strips {x, 15-x} (128 queries each) ->
// every block does exactly 34 s-tile (64-key) iterations. 512 threads = 8 waves.
// S^T MFMA (A=K, B=Q) => P's 4 C-regs are s-contiguous -> single ds_write_b64.
// 1/L folded into V during staging.
__global__ __launch_bounds__(512) void attnout_mfma(const bf16* __restrict__ qkv,
                                                    const bf16* __restrict__ vt,
                                                    const float* __restrict__ Lr,
                                                    bf16* __restrict__ attn) {
    __shared__ short Qs[128 * 72];
    __shared__ short Ps[128 * 72];
    __shared__ short Ks[64 * 72];
    __shared__ short Vt[64 * 72];
    const int tid = threadIdx.x, lane = tid & 63, wv = tid >> 6;
    const int lm = lane & 15, quad = lane >> 4;
    const int bh = blockIdx.y, bb = bh >> 3, hh = bh & 7;
    const bf16* qbase = qkv + (size_t)bb * T_ * 1024 + hh * 64;
    const bf16* kbase = qbase + 512;
    const bf16* vtb = vt + ((size_t)bb * 512 + hh * 64) * T_;
    const float* Lrb = Lr + (size_t)bh * T_;
    for (int half = 0; half < 2; half++) {
        const int strip = half ? 15 - blockIdx.x : blockIdx.x;
        const int tb = strip * 128;
        #pragma unroll
        for (int cc = 0; cc < 2; cc++) {
            int idx = cc * 512 + tid, r = idx >> 3, ch = idx & 7;
            *(s8v*)&Qs[r * 72 + ch * 8] =
                *(const s8v*)(qbase + (size_t)(tb + r) * 1024 + ch * 8);
        }
        f32x4 o[4];
        #pragma unroll
        for (int c = 0; c < 4; c++) {
            f32x4 z = {0.f, 0.f, 0.f, 0.f};
            o[c] = z;
        }
        const int niter = (tb + 128) / 64;
        for (int it = 0; it < niter; it++) {
            const int s0 = it * 64;
            {   // stage K and V*(1/L): 64 rows x 8 chunks = 512 units each
                int r = tid >> 3, ch = tid & 7;
                *(s8v*)&Ks[r * 72 + ch * 8] =
                    *(const s8v*)(kbase + (size_t)(s0 + r) * 1024 + ch * 8);
                s8v vv = *(const s8v*)(vtb + (size_t)r * T_ + s0 + ch * 8);
                s8v vs;
                #pragma unroll
                for (int j = 0; j < 8; j++)
                    vs[j] = f2bs(s2f(vv[j]) * Lrb[s0 + ch * 8 + j]);
                *(s8v*)&Vt[r * 72 + ch * 8] = vs;
            }
            __syncthreads();
            // S^T = K . Q^T : D[row=s local][col=t local]
            b8v bq0 = *(const b8v*)&Qs[(wv * 16 + lm) * 72 + quad * 8];
            b8v bq1 = *(const b8v*)&Qs[(wv * 16 + lm) * 72 + 32 + quad * 8];
            const int t = tb + wv * 16 + lm;
            #pragma unroll
            for (int c = 0; c < 4; c++) {
                b8v ak0 = *(const b8v*)&Ks[(c * 16 + lm) * 72 + quad * 8];
                b8v ak1 = *(const b8v*)&Ks[(c * 16 + lm) * 72 + 32 + quad * 8];
                f32x4 S = {0.f, 0.f, 0.f, 0.f};
                S = MFMA16(ak0, bq0, S);
                S = MFMA16(ak1, bq1, S);
                s4v p;
                #pragma unroll
                for (int reg = 0; reg < 4; reg++) {
                    int s = s0 + c * 16 + quad * 4 + reg;
                    float e = (t >= s) ? __expf(S[reg] * SCALE_) : 0.f;
                    p[reg] = f2bs(e);
                }
                *(s4v*)&Ps[(wv * 16 + lm) * 72 + c * 16 + quad * 4] = p;
            }
            __syncthreads();
            // PV: A = P (m=t,k=s), B = Vt (k=s,n=d)
            b8v ap0 = *(const b8v*)&Ps[(wv * 16 + lm) * 72 + quad * 8];
            b8v ap1 = *(const b8v*)&Ps[(wv * 16 + lm) * 72 + 32 + quad * 8];
            #pragma unroll
            for (int c = 0; c < 4; c++) {
                b8v bv0 = *(const b8v*)&Vt[(c * 16 + lm) * 72 + quad * 8];
                b8v bv1 = *(const b8v*)&Vt[(c * 16 + lm) * 72 + 32 + quad * 8];
                o[c] = MFMA16(ap0, bv0, o[c]);
                o[c] = MFMA16(ap1, bv1, o[c]);
            }
            __syncthreads();
        }
        #pragma unroll
        for (int c = 0; c < 4; c++)
            #pragma unroll
            for (int reg = 0; reg < 4; reg++)
                attn[(size_t)(bb * T_ + tb + wv * 16 + quad * 4 + reg) * C_ + hh * 64 +
                     c * 16 + lm] = f2b(o[c][reg]);
    }
}

extern "C" void kernel_launch(void* const* d_in, const int* in_sizes, int n_in,
                              void* d_out, int out_size, void* d_ws, size_t ws_size,
                              hipStream_t stream) {
    const float* x   = (const float*)d_in[0];
    const float* Wq  = (const float*)d_in[1];
    const float* Wk  = (const float*)d_in[2];
    const float* Wv  = (const float*)d_in[3];
    const float* Wo  = (const float*)d_in[4];
    const float* bo  = (const float*)d_in[5];
    const float* W1  = (const float*)d_in[6];
    const float* b1  = (const float*)d_in[7];
    const float* W2  = (const float*)d_in[8];
    const float* b2  = (const float*)d_in[9];
    const float* g1  = (const float*)d_in[10];
    const float* be1 = (const float*)d_in[11];
    const float* g2  = (const float*)d_in[12];
    const float* be2 = (const float*)d_in[13];
    float* out = (float*)d_out;

    // Workspace (~62 MB). Region A (32 MB) is time-multiplexed:
    //   [qkvb 16MB | attn 8MB | hbuf 8MB]  then reused whole as ff1 (32MB).
    char* w = (char*)d_ws;
    auto alloc = [&](size_t bytes) -> void* {
        void* p = (void*)w;
        w += (bytes + 255) & ~(size_t)255;
        return p;
    };
    bf16* regionA = (bf16*)alloc((size_t)BT_ * 2048 * sizeof(bf16));  // 32MB
    bf16* qkvb = regionA;                                // [BT][1024] (q|k)
    bf16* attn = regionA + (size_t)BT_ * 1024;           // [BT][512]
    bf16* hbuf = regionA + (size_t)BT_ * 1536;           // [BT][512]
    bf16* ff1  = regionA;                                // [BT][2048]
    bf16* x1     = (bf16*)alloc((size_t)BT_ * C_ * sizeof(bf16));
    bf16* h2     = (bf16*)alloc((size_t)BT_ * C_ * sizeof(bf16));
    bf16* vt     = (bf16*)alloc((size_t)B_ * 512 * T_ * sizeof(bf16));   // [B][H*D][T]
    bf16* WqkvT  = (bf16*)alloc((size_t)1536 * C_ * sizeof(bf16));       // [1536][512]
    bf16* WoT    = (bf16*)alloc((size_t)C_ * C_ * sizeof(bf16));
    bf16* W1T    = (bf16*)alloc((size_t)C4_ * C_ * sizeof(bf16));        // [2048][512]
    bf16* W2T    = (bf16*)alloc((size_t)C_ * C4_ * sizeof(bf16));        // [512][2048]
    float* Lr    = (float*)alloc((size_t)B_ * H_ * T_ * sizeof(float));

    // Weight transposes (fp32 -> bf16 [N][K])
    qkv_transpose<<<dim3(8, 8), 256, 0, stream>>>(Wq, WqkvT);
    qkv_transpose<<<dim3(8, 8), 256, 0, stream>>>(Wk, WqkvT + (size_t)512 * C_);
    qkv_transpose<<<dim3(8, 8), 256, 0, stream>>>(Wv, WqkvT + (size_t)1024 * C_);
    transpose_cvt<<<dim3(8, 8), 256, 0, stream>>>(Wo, WoT, 512, 512);
    transpose_cvt<<<dim3(8, 32), 256, 0, stream>>>(W1, W1T, 512, 2048);
    transpose_cvt<<<dim3(32, 8), 256, 0, stream>>>(W2, W2T, 2048, 512);

    // 1. h = LN(x)
    ln_kernel<float><<<BT_, 256, 0, stream>>>(x, g1, be1, hbuf);
    // 2. QKV GEMM: [8192,1536,512]; q,k -> qkvb, v -> vt (transposed)
    mfma_gemm<4><<<dim3(BT_ / 128, 1536 / 128), 256, 0, stream>>>(
        hbuf, WqkvT, nullptr, nullptr, nullptr, nullptr, nullptr, qkvb, vt,
        BT_, 1536, C_);
    // 3. column-sum reciprocals
    colsum_mfma<<<dim3(8, B_ * H_), 512, 0, stream>>>(qkvb, Lr);
    // 4. attention output
    attnout_mfma<<<dim3(8, B_ * H_), 512, 0, stream>>>(qkvb, vt, Lr, attn);
    // 5. x1 = x + attn @ Wo + bo
    mfma_gemm<2><<<dim3(BT_ / 128, C_ / 128), 256, 0, stream>>>(
        attn, WoT, bo, x, nullptr, x1, nullptr, nullptr, nullptr, BT_, C_, C_);
    // 6. h2 = LN(x1)
    ln_kernel<bf16><<<BT_, 256, 0, stream>>>(x1, g2, be2, h2);
    // 7. ff1 = relu(h2 @ W1 + b1)
    mfma_gemm<1><<<dim3(BT_ / 128, C4_ / 128), 256, 0, stream>>>(
        h2, W1T, b1, nullptr, nullptr, ff1, nullptr, nullptr, nullptr, BT_, C4_, C_);
    // 8. out = x1 + ff1 @ W2 + b2
    mfma_gemm<3><<<dim3(BT_ / 128, C_ / 128), 256, 0, stream>>>(
        ff1, W2T, b2, nullptr, x1, nullptr, out, nullptr, nullptr, BT_, C_, C4_);
}

// Round 5
// 297.499 us; speedup vs baseline: 12.2853x; 1.1343x over previous
//
#include <hip/hip_runtime.h>
#include <hip/hip_bf16.h>

// Block_4776003633552: transformer block, B=4 T=2048 C=512 H=8 D=64. fp32 I/O.
// Reference quirks: scale = C^-0.5; softmax over QUERY axis (axis=-2) =>
//   out_t = sum_{s<=t} exp(sc*q_t.k_s) * v_s / L_s,  L_s = sum_{t>=s} exp(sc*q_t.k_s).
// Round 5: attention XCD-swizzled (grid x = bh so same-bh blocks share an XCD L2),
// single-barrier double-buffered pipeline (reg-prefetch of streamed tile issued
// right after the barrier, overlapping MFMA/exp), transposes merged to 1 launch.

typedef __hip_bfloat16 bf16;
typedef __bf16 b8v __attribute__((ext_vector_type(8)));   // MFMA A/B fragment (8 bf16)
typedef float  f32x4 __attribute__((ext_vector_type(4))); // MFMA C/D fragment
typedef short  s8v  __attribute__((ext_vector_type(8)));  // 16B bf16 copy chunk
typedef short  s4v  __attribute__((ext_vector_type(4)));  // 8B packed P write

#define B_   4
#define T_   2048
#define C_   512
#define H_   8
#define D_   64
#define BT_  (B_ * T_)
#define C4_  (4 * C_)
#define EPS_ 1e-5f
#define SCALE_ 0.04419417382415922f  // 1/sqrt(512)

#define MFMA16(a, b, c) __builtin_amdgcn_mfma_f32_16x16x32_bf16(a, b, c, 0, 0, 0)

static __device__ __forceinline__ float b2f(bf16 x) { return __bfloat162float(x); }
static __device__ __forceinline__ bf16  f2b(float x) { return __float2bfloat16(x); }
static __device__ __forceinline__ short f2bs(float x) {
    bf16 h = f2b(x);
    return __builtin_bit_cast(short, h);
}
static __device__ __forceinline__ float s2f(short x) {
    return b2f(__builtin_bit_cast(bf16, x));
}

// ---------------- LayerNorm over C=512, one block per row ----------------
static __device__ __forceinline__ float ldv(const float* p) { return *p; }
static __device__ __forceinline__ float ldv(const bf16* p)  { return b2f(*p); }

template <typename TIN>
__global__ __launch_bounds__(256) void ln_kernel(const TIN* __restrict__ x,
                                                 const float* __restrict__ g,
                                                 const float* __restrict__ be,
                                                 bf16* __restrict__ out) {
    const int row = blockIdx.x;
    const int tid = threadIdx.x;
    const TIN* xr = x + (size_t)row * C_;
    float v0 = ldv(xr + tid * 2);
    float v1 = ldv(xr + tid * 2 + 1);
    float s = v0 + v1;
    float sq = v0 * v0 + v1 * v1;
    #pragma unroll
    for (int o = 32; o > 0; o >>= 1) {
        s += __shfl_down(s, o);
        sq += __shfl_down(sq, o);
    }
    __shared__ float ws[8], wsq[8];
    const int wid = tid >> 6, lane = tid & 63;
    if (lane == 0) { ws[wid] = s; wsq[wid] = sq; }
    __syncthreads();
    if (tid == 0) {
        float ts = 0.f, tq = 0.f;
        #pragma unroll
        for (int i = 0; i < 4; i++) { ts += ws[i]; tq += wsq[i]; }
        float mu = ts * (1.f / C_);
        float var = tq * (1.f / C_) - mu * mu;
        ws[4] = mu;
        wsq[4] = rsqrtf(var + EPS_);
    }
    __syncthreads();
    const float mu = ws[4], rstd = wsq[4];
    bf16* orow = out + (size_t)row * C_;
    orow[tid * 2]     = f2b((v0 - mu) * rstd * g[tid * 2]     + be[tid * 2]);
    orow[tid * 2 + 1] = f2b((v1 - mu) * rstd * g[tid * 2 + 1] + be[tid * 2 + 1]);
}

// ---------------- All weight transposes in one launch (768 blocks) ----------------
// 0-191: Wq/Wk/Wv per-head -> WqkvT; 192-255: Wo; 256-511: W1; 512-767: W2.
__global__ __launch_bounds__(256) void transpose_all(const float* __restrict__ Wq,
                                                     const float* __restrict__ Wk,
                                                     const float* __restrict__ Wv,
                                                     const float* __restrict__ Wo,
                                                     const float* __restrict__ W1,
                                                     const float* __restrict__ W2,
                                                     bf16* __restrict__ WqkvT,
                                                     bf16* __restrict__ WoT,
                                                     bf16* __restrict__ W1T,
                                                     bf16* __restrict__ W2T) {
    __shared__ float Ts[64][65];
    const int tid = threadIdx.x;
    const int id = blockIdx.x;
    if (id < 192) {
        const int sub = id / 64, rem = id % 64;
        const int x = rem & 7, hh = rem >> 3;
        const float* src = (sub == 0 ? Wq : sub == 1 ? Wk : Wv) + (size_t)hh * C_ * D_;
        bf16* dst = WqkvT + (size_t)sub * 512 * C_;
        const int c0 = x * 64;
        #pragma unroll
        for (int p = 0; p < 16; p++) {
            int idx = p * 256 + tid, i = idx >> 6, j = idx & 63;
            Ts[i][j] = src[(size_t)(c0 + i) * D_ + j];
        }
        __syncthreads();
        #pragma unroll
        for (int p = 0; p < 16; p++) {
            int idx = p * 256 + tid, j = idx >> 6, i = idx & 63;
            dst[(size_t)(hh * 64 + j) * C_ + c0 + i] = f2b(Ts[i][j]);
        }
    } else {
        const float* src;
        bf16* dst;
        int r0, c0, R, Cc;
        if (id < 256) {
            int rem = id - 192;
            src = Wo; dst = WoT; R = 512; Cc = 512;
            r0 = (rem & 7) * 64; c0 = (rem >> 3) * 64;
        } else if (id < 512) {
            int rem = id - 256;
            src = W1; dst = W1T; R = 512; Cc = 2048;
            r0 = (rem & 7) * 64; c0 = (rem >> 3) * 64;
        } else {
            int rem = id - 512;
            src = W2; dst = W2T; R = 2048; Cc = 512;
            r0 = (rem & 31) * 64; c0 = (rem >> 5) * 64;
        }
        #pragma unroll
        for (int p = 0; p < 16; p++) {
            int idx = p * 256 + tid, i = idx >> 6, j = idx & 63;
            Ts[i][j] = src[(size_t)(r0 + i) * Cc + c0 + j];
        }
        __syncthreads();
        #pragma unroll
        for (int p = 0; p < 16; p++) {
            int idx = p * 256 + tid, j = idx >> 6, i = idx & 63;
            dst[(size_t)(c0 + j) * R + r0 + i] = f2b(Ts[i][j]);
        }
    }
}

// ---------------- MFMA GEMM: C[M,N] = A[M,K] @ Bt[N,K]^T ----------------
// 128x128 tile, BK=32, 256 threads = 4 waves (2x2 of 64x64), 4x4 mfma tiles/wave.
// MODE 1: +bias +relu -> bf16.  MODE 2: +bias +fp32 res -> bf16.
// MODE 3: +bias +bf16 res -> fp32.  MODE 4: QKV split (q,k -> qkvb; v -> vt).
template <int MODE>
__global__ __launch_bounds__(256) void mfma_gemm(const bf16* __restrict__ A,
                                                 const bf16* __restrict__ Bt,
                                                 const float* __restrict__ bias,
                                                 const float* __restrict__ resf,
                                                 const bf16* __restrict__ resb,
                                                 bf16* __restrict__ outb,
                                                 float* __restrict__ outf,
                                                 bf16* __restrict__ qkvb,
                                                 bf16* __restrict__ vt,
                                                 int M, int N, int K) {
    __shared__ short As[128 * 32];
    __shared__ short Bs[128 * 32];
    const int tid = threadIdx.x;
    const int lane = tid & 63, wv = tid >> 6;
    const int wm = wv >> 1, wn = wv & 1;
    const int m0 = blockIdx.x * 128, n0 = blockIdx.y * 128;
    const int lrow = lane >> 2, lk = (lane & 3) * 8;
    const int lm = lane & 15, quad = lane >> 4;

    f32x4 acc[4][4];
    #pragma unroll
    for (int r = 0; r < 4; r++)
        #pragma unroll
        for (int c = 0; c < 4; c++) {
            f32x4 z = {0.f, 0.f, 0.f, 0.f};
            acc[r][c] = z;
        }

    for (int k0 = 0; k0 < K; k0 += 32) {
        #pragma unroll
        for (int cc = 0; cc < 2; cc++) {
            const int row = cc * 64 + wv * 16 + lrow;
            const bf16* ga = A + (size_t)(m0 + row) * K + k0 + lk;
            __builtin_amdgcn_global_load_lds(
                (const __attribute__((address_space(1))) void*)ga,
                (__attribute__((address_space(3))) void*)&As[(cc * 64 + wv * 16) * 32],
                16, 0, 0);
            const bf16* gb = Bt + (size_t)(n0 + row) * K + k0 + lk;
            __builtin_amdgcn_global_load_lds(
                (const __attribute__((address_space(1))) void*)gb,
                (__attribute__((address_space(3))) void*)&Bs[(cc * 64 + wv * 16) * 32],
                16, 0, 0);
        }
        __syncthreads();
        b8v af[4], bfr[4];
        #pragma unroll
        for (int r = 0; r < 4; r++)
            af[r] = *(const b8v*)&As[(wm * 64 + r * 16 + lm) * 32 + quad * 8];
        #pragma unroll
        for (int c = 0; c < 4; c++)
            bfr[c] = *(const b8v*)&Bs[(wn * 64 + c * 16 + lm) * 32 + quad * 8];
        #pragma unroll
        for (int r = 0; r < 4; r++)
            #pragma unroll
            for (int c = 0; c < 4; c++)
                acc[r][c] = MFMA16(af[r], bfr[c], acc[r][c]);
        __syncthreads();
    }

    #pragma unroll
    for (int r = 0; r < 4; r++) {
        const int mbase = m0 + wm * 64 + r * 16 + quad * 4;
        #pragma unroll
        for (int c = 0; c < 4; c++) {
            const int n = n0 + wn * 64 + c * 16 + lm;
            #pragma unroll
            for (int reg = 0; reg < 4; reg++) {
                const int m = mbase + reg;
                float v = acc[r][c][reg];
                if (MODE == 1) {
                    v += bias[n];
                    v = fmaxf(v, 0.f);
                    outb[(size_t)m * N + n] = f2b(v);
                } else if (MODE == 2) {
                    v += bias[n] + resf[(size_t)m * N + n];
                    outb[(size_t)m * N + n] = f2b(v);
                } else if (MODE == 3) {
                    v += bias[n] + b2f(resb[(size_t)m * N + n]);
                    outf[(size_t)m * N + n] = v;
                } else {  // MODE 4: QKV
                    if (n < 1024) {
                        qkvb[(size_t)m * 1024 + n] = f2b(v);
                    } else {
                        vt[((size_t)(m >> 11) * 512 + (n - 1024)) * T_ + (m & (T_ - 1))] =
                            f2b(v);
                    }
                }
            }
        }
    }
}

// ---------------- Pass 1: Lr[s] = 1 / sum_{t>=s} exp(sc*q_t.k_s) ----------------
// grid (bh=32, pair=8): same-bh blocks share an XCD (id = bh + 32*pair, %8 = h).
// Strip-paired {x, 15-x} => every block does exactly 17 Q-tile iterations.
// Q double-buffered, single barrier/iter, reg prefetch issued after the barrier.
__global__ __launch_bounds__(512) void colsum_mfma(const bf16* __restrict__ qkv,
                                                   float* __restrict__ Lr) {
    __shared__ short Ks[128 * 72];
    __shared__ short Qs[2][128 * 72];
    __shared__ float red[8][128];
    const int tid = threadIdx.x, lane = tid & 63, wv = tid >> 6;
    const int lm = lane & 15, quad = lane >> 4;
    const int bh = blockIdx.x, bb = bh >> 3, hh = bh & 7;
    const bf16* qbase = qkv + (size_t)bb * T_ * 1024 + hh * 64;
    const bf16* kbase = qbase + 512;
    const int rA = tid >> 3, rB = 64 + (tid >> 3), ch = tid & 7;
    for (int half = 0; half < 2; half++) {
        const int strip = half ? 15 - (int)blockIdx.y : (int)blockIdx.y;
        const int s0 = strip * 128;
        // stage resident K (read after iter-0 barrier)
        *(s8v*)&Ks[rA * 72 + ch * 8] =
            *(const s8v*)(kbase + (size_t)(s0 + rA) * 1024 + ch * 8);
        *(s8v*)&Ks[rB * 72 + ch * 8] =
            *(const s8v*)(kbase + (size_t)(s0 + rB) * 1024 + ch * 8);
        // preload Q tile 0
        s8v qrA = *(const s8v*)(qbase + (size_t)(s0 + rA) * 1024 + ch * 8);
        s8v qrB = *(const s8v*)(qbase + (size_t)(s0 + rB) * 1024 + ch * 8);
        float csum[8] = {};
        const int niter = (T_ - s0) / 128;
        for (int it = 0; it < niter; it++) {
            const int buf = it & 1;
            *(s8v*)&Qs[buf][rA * 72 + ch * 8] = qrA;
            *(s8v*)&Qs[buf][rB * 72 + ch * 8] = qrB;
            __syncthreads();
            if (it + 1 < niter) {
                const int t1 = s0 + (it + 1) * 128;
                qrA = *(const s8v*)(qbase + (size_t)(t1 + rA) * 1024 + ch * 8);
                qrB = *(const s8v*)(qbase + (size_t)(t1 + rB) * 1024 + ch * 8);
            }
            const int t0 = s0 + it * 128;
            b8v aq0 = *(const b8v*)&Qs[buf][(wv * 16 + lm) * 72 + quad * 8];
            b8v aq1 = *(const b8v*)&Qs[buf][(wv * 16 + lm) * 72 + 32 + quad * 8];
            #pragma unroll
            for (int c = 0; c < 8; c++) {
                b8v bk0 = *(const b8v*)&Ks[(c * 16 + lm) * 72 + quad * 8];
                b8v bk1 = *(const b8v*)&Ks[(c * 16 + lm) * 72 + 32 + quad * 8];
                f32x4 S = {0.f, 0.f, 0.f, 0.f};
                S = MFMA16(aq0, bk0, S);
                S = MFMA16(aq1, bk1, S);
                const int s = s0 + c * 16 + lm;
                #pragma unroll
                for (int reg = 0; reg < 4; reg++) {
                    int t = t0 + wv * 16 + quad * 4 + reg;
                    if (t >= s) csum[c] += __expf(S[reg] * SCALE_);
                }
            }
        }
        __syncthreads();  // all Qs/Ks reads done before reduction & restage
        #pragma unroll
        for (int c = 0; c < 8; c++) {
            float v = csum[c];
            v += __shfl_xor(v, 16);
            v += __shfl_xor(v, 32);
            if (lane < 16) red[wv][c * 16 + lane] = v;
        }
        __syncthreads();
        if (tid < 128) {
            float s = 0.f;
            #pragma unroll
            for (int i = 0; i < 8; i++) s += red[i][tid];
            Lr[(size_t)bh * T_ + s0 + tid] = 1.0f / s;
        }
        __syncthreads();
    }
}

// ---------------- Pass 2: out_t = sum_{s<=t} exp(sc*q_t.k_s) * (v_s * Lr_s) ----------------
// grid (bh=32, pair=8), XCD-swizzled. K/V double-buffered, single barrier/iter,
// reg prefetch after barrier. S^T MFMA => P packs as ds_write_b64, P wave-local.
__global__ __launch_bounds__(512) void attnout_mfma(const bf16* __restrict__ qkv,
                                                    const bf16* __restrict__ vt,
                                                    const float* __restrict__ Lr,
                                                    bf16* __restrict__ attn) {
    __shared__ short Qs[128 * 72];
    __shared__ short Ps[128 * 72];
    __shared__ short Ks[2][64 * 72];
    __shared__ short Vt[2][64 * 72];
    const int tid = threadIdx.x, lane = tid & 63, wv = tid >> 6;
    const int lm = lane & 15, quad = lane >> 4;
    const int bh = blockIdx.x, bb = bh >> 3, hh = bh & 7;
    const bf16* qbase = qkv + (size_t)bb * T_ * 1024 + hh * 64;
    const bf16* kbase = qbase + 512;
    const bf16* vtb = vt + ((size_t)bb * 512 + hh * 64) * T_;
    const float* Lrb = Lr + (size_t)bh * T_;
    const int r = tid >> 3, ch = tid & 7;
    for (int half = 0; half < 2; half++) {
        const int strip = half ? 15 - (int)blockIdx.y : (int)blockIdx.y;
        const int tb = strip * 128;
        // stage Q strip (read after iter-0 barrier)
        #pragma unroll
        for (int cc = 0; cc < 2; cc++) {
            int idx = cc * 512 + tid, qr = idx >> 3, qc = idx & 7;
            *(s8v*)&Qs[qr * 72 + qc * 8] =
                *(const s8v*)(qbase + (size_t)(tb + qr) * 1024 + qc * 8);
        }
        // preload K/V/Lr tile 0
        s8v kreg = *(const s8v*)(kbase + (size_t)r * 1024 + ch * 8);
        s8v vreg = *(const s8v*)(vtb + (size_t)r * T_ + ch * 8);
        float4 lr0 = *(const float4*)(Lrb + ch * 8);
        float4 lr1 = *(const float4*)(Lrb + ch * 8 + 4);
        f32x4 o[4];
        #pragma unroll
        for (int c = 0; c < 4; c++) {
            f32x4 z = {0.f, 0.f, 0.f, 0.f};
            o[c] = z;
        }
        const int niter = (tb + 128) / 64;
        for (int it = 0; it < niter; it++) {
            const int s0 = it * 64, buf = it & 1;
            // scale V by 1/L and commit staged tile
            s8v vs;
            vs[0] = f2bs(s2f(vreg[0]) * lr0.x);
            vs[1] = f2bs(s2f(vreg[1]) * lr0.y);
            vs[2] = f2bs(s2f(vreg[2]) * lr0.z);
            vs[3] = f2bs(s2f(vreg[3]) * lr0.w);
            vs[4] = f2bs(s2f(vreg[4]) * lr1.x);
            vs[5] = f2bs(s2f(vreg[5]) * lr1.y);
            vs[6] = f2bs(s2f(vreg[6]) * lr1.z);
            vs[7] = f2bs(s2f(vreg[7]) * lr1.w);
            *(s8v*)&Ks[buf][r * 72 + ch * 8] = kreg;
            *(s8v*)&Vt[buf][r * 72 + ch * 8] = vs;
            __syncthreads();
            if (it + 1 < niter) {
                const int s1 = s0 + 64;
                kreg = *(const s8v*)(kbase + (size_t)(s1 + r) * 1024 + ch * 8);
                vreg = *(const s8v*)(vtb + (size_t)r * T_ + s1 + ch * 8);
                lr0 = *(const float4*)(Lrb + s1 + ch * 8);
                lr1 = *(const float4*)(Lrb + s1 + ch * 8 + 4);
            }
            // S^T = K . Q^T : D[row=s local][col=t local]
            b8v bq0 = *(const b8v*)&Qs[(wv * 16 + lm) * 72 + quad * 8];
            b8v bq1 = *(const b8v*)&Qs[(wv * 16 + lm) * 72 + 32 + quad * 8];
            const int t = tb + wv * 16 + lm;
            #pragma unroll
            for (int c = 0; c < 4; c++) {
                b8v ak0 = *(const b8v*)&Ks[buf][(c * 16 + lm) * 72 + quad * 8];
                b8v ak1 = *(const b8v*)&Ks[buf][(c * 16 + lm) * 72 + 32 + quad * 8];
                f32x4 S = {0.f, 0.f, 0.f, 0.f};
                S = MFMA16(ak0, bq0, S);
                S = MFMA16(ak1, bq1, S);
                s4v p;
                #pragma unroll
                for (int reg = 0; reg < 4; reg++) {
                    int s = s0 + c * 16 + quad * 4 + reg;
                    float e = (t >= s) ? __expf(S[reg] * SCALE_) : 0.f;
                    p[reg] = f2bs(e);
                }
                *(s4v*)&Ps[(wv * 16 + lm) * 72 + c * 16 + quad * 4] = p;
            }
            // PV: A = P (wave-local rows), B = Vt
            b8v ap0 = *(const b8v*)&Ps[(wv * 16 + lm) * 72 + quad * 8];
            b8v ap1 = *(const b8v*)&Ps[(wv * 16 + lm) * 72 + 32 + quad * 8];
            #pragma unroll
            for (int c = 0; c < 4; c++) {
                b8v bv0 = *(const b8v*)&Vt[buf][(c * 16 + lm) * 72 + quad * 8];
                b8v bv1 = *(const b8v*)&Vt[buf][(c * 16 + lm) * 72 + 32 + quad * 8];
                o[c] = MFMA16(ap0, bv0, o[c]);
                o[c] = MFMA16(ap1, bv1, o[c]);
            }
        }
        #pragma unroll
        for (int c = 0; c < 4; c++)
            #pragma unroll
            for (int reg = 0; reg < 4; reg++)
                attn[(size_t)(bb * T_ + tb + wv * 16 + quad * 4 + reg) * C_ + hh * 64 +
                     c * 16 + lm] = f2b(o[c][reg]);
        __syncthreads();  // protect Qs/Ks/Vt restage in next half
    }
}

extern "C" void kernel_launch(void* const* d_in, const int* in_sizes, int n_in,
                              void* d_out, int out_size, void* d_ws, size_t ws_size,
                              hipStream_t stream) {
    const float* x   = (const float*)d_in[0];
    const float* Wq  = (const float*)d_in[1];
    const float* Wk  = (const float*)d_in[2];
    const float* Wv  = (const float*)d_in[3];
    const float* Wo  = (const float*)d_in[4];
    const float* bo  = (const float*)d_in[5];
    const float* W1  = (const float*)d_in[6];
    const float* b1  = (const float*)d_in[7];
    const float* W2  = (const float*)d_in[8];
    const float* b2  = (const float*)d_in[9];
    const float* g1  = (const float*)d_in[10];
    const float* be1 = (const float*)d_in[11];
    const float* g2  = (const float*)d_in[12];
    const float* be2 = (const float*)d_in[13];
    float* out = (float*)d_out;

    // Workspace (~62 MB). Region A (32 MB) is time-multiplexed:
    //   [qkvb 16MB | attn 8MB | hbuf 8MB]  then reused whole as ff1 (32MB).
    char* w = (char*)d_ws;
    auto alloc = [&](size_t bytes) -> void* {
        void* p = (void*)w;
        w += (bytes + 255) & ~(size_t)255;
        return p;
    };
    bf16* regionA = (bf16*)alloc((size_t)BT_ * 2048 * sizeof(bf16));  // 32MB
    bf16* qkvb = regionA;                                // [BT][1024] (q|k)
    bf16* attn = regionA + (size_t)BT_ * 1024;           // [BT][512]
    bf16* hbuf = regionA + (size_t)BT_ * 1536;           // [BT][512]
    bf16* ff1  = regionA;                                // [BT][2048]
    bf16* x1     = (bf16*)alloc((size_t)BT_ * C_ * sizeof(bf16));
    bf16* h2     = (bf16*)alloc((size_t)BT_ * C_ * sizeof(bf16));
    bf16* vt     = (bf16*)alloc((size_t)B_ * 512 * T_ * sizeof(bf16));   // [B][H*D][T]
    bf16* WqkvT  = (bf16*)alloc((size_t)1536 * C_ * sizeof(bf16));       // [1536][512]
    bf16* WoT    = (bf16*)alloc((size_t)C_ * C_ * sizeof(bf16));
    bf16* W1T    = (bf16*)alloc((size_t)C4_ * C_ * sizeof(bf16));        // [2048][512]
    bf16* W2T    = (bf16*)alloc((size_t)C_ * C4_ * sizeof(bf16));        // [512][2048]
    float* Lr    = (float*)alloc((size_t)B_ * H_ * T_ * sizeof(float));

    // All weight transposes (fp32 -> bf16 [N][K]) in one launch
    transpose_all<<<768, 256, 0, stream>>>(Wq, Wk, Wv, Wo, W1, W2,
                                           WqkvT, WoT, W1T, W2T);
    // 1. h = LN(x)
    ln_kernel<float><<<BT_, 256, 0, stream>>>(x, g1, be1, hbuf);
    // 2. QKV GEMM: [8192,1536,512]; q,k -> qkvb, v -> vt (transposed)
    mfma_gemm<4><<<dim3(BT_ / 128, 1536 / 128), 256, 0, stream>>>(
        hbuf, WqkvT, nullptr, nullptr, nullptr, nullptr, nullptr, qkvb, vt,
        BT_, 1536, C_);
    // 3. column-sum reciprocals (XCD-swizzled grid)
    colsum_mfma<<<dim3(B_ * H_, 8), 512, 0, stream>>>(qkvb, Lr);
    // 4. attention output (XCD-swizzled grid)
    attnout_mfma<<<dim3(B_ * H_, 8), 512, 0, stream>>>(qkvb, vt, Lr, attn);
    // 5. x1 = x + attn @ Wo + bo
    mfma_gemm<2><<<dim3(BT_ / 128, C_ / 128), 256, 0, stream>>>(
        attn, WoT, bo, x, nullptr, x1, nullptr, nullptr, nullptr, BT_, C_, C_);
    // 6. h2 = LN(x1)
    ln_kernel<bf16><<<BT_, 256, 0, stream>>>(x1, g2, be2, h2);
    // 7. ff1 = relu(h2 @ W1 + b1)
    mfma_gemm<1><<<dim3(BT_ / 128, C4_ / 128), 256, 0, stream>>>(
        h2, W1T, b1, nullptr, nullptr, ff1, nullptr, nullptr, nullptr, BT_, C4_, C_);
    // 8. out = x1 + ff1 @ W2 + b2
    mfma_gemm<3><<<dim3(BT_ / 128, C_ / 128), 256, 0, stream>>>(
        ff1, W2T, b2, nullptr, x1, nullptr, out, nullptr, nullptr, BT_, C_, C4_);
}

// Round 6
// 293.148 us; speedup vs baseline: 12.4676x; 1.0148x over previous
//
#include <hip/hip_runtime.h>
#include <hip/hip_bf16.h>

// Block_4776003633552: transformer block, B=4 T=2048 C=512 H=8 D=64. fp32 I/O.
// Reference quirks: scale = C^-0.5; softmax over QUERY axis (axis=-2) =>
//   out_t = sum_{s<=t} exp(sc*q_t.k_s) * v_s / L_s,  L_s = sum_{t>=s} exp(sc*q_t.k_s).
// Round 6: Wo and W2 GEMMs moved to 512-thread blocks (8 waves, same 128x128 tile)
// -> 2 waves/SIMD instead of 1 (their grids are only 256 blocks = 1 block/CU).
// Attention kernels unchanged from round 5 (XCD-swizzled, single-barrier pipeline).

typedef __hip_bfloat16 bf16;
typedef __bf16 b8v __attribute__((ext_vector_type(8)));   // MFMA A/B fragment (8 bf16)
typedef float  f32x4 __attribute__((ext_vector_type(4))); // MFMA C/D fragment
typedef short  s8v  __attribute__((ext_vector_type(8)));  // 16B bf16 copy chunk
typedef short  s4v  __attribute__((ext_vector_type(4)));  // 8B packed P write

#define B_   4
#define T_   2048
#define C_   512
#define H_   8
#define D_   64
#define BT_  (B_ * T_)
#define C4_  (4 * C_)
#define EPS_ 1e-5f
#define SCALE_ 0.04419417382415922f  // 1/sqrt(512)

#define MFMA16(a, b, c) __builtin_amdgcn_mfma_f32_16x16x32_bf16(a, b, c, 0, 0, 0)

static __device__ __forceinline__ float b2f(bf16 x) { return __bfloat162float(x); }
static __device__ __forceinline__ bf16  f2b(float x) { return __float2bfloat16(x); }
static __device__ __forceinline__ short f2bs(float x) {
    bf16 h = f2b(x);
    return __builtin_bit_cast(short, h);
}
static __device__ __forceinline__ float s2f(short x) {
    return b2f(__builtin_bit_cast(bf16, x));
}

// ---------------- LayerNorm over C=512, one block per row ----------------
static __device__ __forceinline__ float ldv(const float* p) { return *p; }
static __device__ __forceinline__ float ldv(const bf16* p)  { return b2f(*p); }

template <typename TIN>
__global__ __launch_bounds__(256) void ln_kernel(const TIN* __restrict__ x,
                                                 const float* __restrict__ g,
                                                 const float* __restrict__ be,
                                                 bf16* __restrict__ out) {
    const int row = blockIdx.x;
    const int tid = threadIdx.x;
    const TIN* xr = x + (size_t)row * C_;
    float v0 = ldv(xr + tid * 2);
    float v1 = ldv(xr + tid * 2 + 1);
    float s = v0 + v1;
    float sq = v0 * v0 + v1 * v1;
    #pragma unroll
    for (int o = 32; o > 0; o >>= 1) {
        s += __shfl_down(s, o);
        sq += __shfl_down(sq, o);
    }
    __shared__ float ws[8], wsq[8];
    const int wid = tid >> 6, lane = tid & 63;
    if (lane == 0) { ws[wid] = s; wsq[wid] = sq; }
    __syncthreads();
    if (tid == 0) {
        float ts = 0.f, tq = 0.f;
        #pragma unroll
        for (int i = 0; i < 4; i++) { ts += ws[i]; tq += wsq[i]; }
        float mu = ts * (1.f / C_);
        float var = tq * (1.f / C_) - mu * mu;
        ws[4] = mu;
        wsq[4] = rsqrtf(var + EPS_);
    }
    __syncthreads();
    const float mu = ws[4], rstd = wsq[4];
    bf16* orow = out + (size_t)row * C_;
    orow[tid * 2]     = f2b((v0 - mu) * rstd * g[tid * 2]     + be[tid * 2]);
    orow[tid * 2 + 1] = f2b((v1 - mu) * rstd * g[tid * 2 + 1] + be[tid * 2 + 1]);
}

// ---------------- All weight transposes in one launch (768 blocks) ----------------
__global__ __launch_bounds__(256) void transpose_all(const float* __restrict__ Wq,
                                                     const float* __restrict__ Wk,
                                                     const float* __restrict__ Wv,
                                                     const float* __restrict__ Wo,
                                                     const float* __restrict__ W1,
                                                     const float* __restrict__ W2,
                                                     bf16* __restrict__ WqkvT,
                                                     bf16* __restrict__ WoT,
                                                     bf16* __restrict__ W1T,
                                                     bf16* __restrict__ W2T) {
    __shared__ float Ts[64][65];
    const int tid = threadIdx.x;
    const int id = blockIdx.x;
    if (id < 192) {
        const int sub = id / 64, rem = id % 64;
        const int x = rem & 7, hh = rem >> 3;
        const float* src = (sub == 0 ? Wq : sub == 1 ? Wk : Wv) + (size_t)hh * C_ * D_;
        bf16* dst = WqkvT + (size_t)sub * 512 * C_;
        const int c0 = x * 64;
        #pragma unroll
        for (int p = 0; p < 16; p++) {
            int idx = p * 256 + tid, i = idx >> 6, j = idx & 63;
            Ts[i][j] = src[(size_t)(c0 + i) * D_ + j];
        }
        __syncthreads();
        #pragma unroll
        for (int p = 0; p < 16; p++) {
            int idx = p * 256 + tid, j = idx >> 6, i = idx & 63;
            dst[(size_t)(hh * 64 + j) * C_ + c0 + i] = f2b(Ts[i][j]);
        }
    } else {
        const float* src;
        bf16* dst;
        int r0, c0, R, Cc;
        if (id < 256) {
            int rem = id - 192;
            src = Wo; dst = WoT; R = 512; Cc = 512;
            r0 = (rem & 7) * 64; c0 = (rem >> 3) * 64;
        } else if (id < 512) {
            int rem = id - 256;
            src = W1; dst = W1T; R = 512; Cc = 2048;
            r0 = (rem & 7) * 64; c0 = (rem >> 3) * 64;
        } else {
            int rem = id - 512;
            src = W2; dst = W2T; R = 2048; Cc = 512;
            r0 = (rem & 31) * 64; c0 = (rem >> 5) * 64;
        }
        #pragma unroll
        for (int p = 0; p < 16; p++) {
            int idx = p * 256 + tid, i = idx >> 6, j = idx & 63;
            Ts[i][j] = src[(size_t)(r0 + i) * Cc + c0 + j];
        }
        __syncthreads();
        #pragma unroll
        for (int p = 0; p < 16; p++) {
            int idx = p * 256 + tid, j = idx >> 6, i = idx & 63;
            dst[(size_t)(c0 + j) * R + r0 + i] = f2b(Ts[i][j]);
        }
    }
}

// ---------------- MFMA GEMM (256 thr): C[M,N] = A[M,K] @ Bt[N,K]^T ----------------
// 128x128 tile, BK=32, 4 waves (2x2 of 64x64), 4x4 mfma tiles/wave.
// MODE 1: +bias +relu -> bf16.  MODE 4: QKV split (q,k -> qkvb; v -> vt).
template <int MODE>
__global__ __launch_bounds__(256) void mfma_gemm(const bf16* __restrict__ A,
                                                 const bf16* __restrict__ Bt,
                                                 const float* __restrict__ bias,
                                                 bf16* __restrict__ outb,
                                                 bf16* __restrict__ qkvb,
                                                 bf16* __restrict__ vt,
                                                 int M, int N, int K) {
    __shared__ short As[128 * 32];
    __shared__ short Bs[128 * 32];
    const int tid = threadIdx.x;
    const int lane = tid & 63, wv = tid >> 6;
    const int wm = wv >> 1, wn = wv & 1;
    const int m0 = blockIdx.x * 128, n0 = blockIdx.y * 128;
    const int lrow = lane >> 2, lk = (lane & 3) * 8;
    const int lm = lane & 15, quad = lane >> 4;

    f32x4 acc[4][4];
    #pragma unroll
    for (int r = 0; r < 4; r++)
        #pragma unroll
        for (int c = 0; c < 4; c++) {
            f32x4 z = {0.f, 0.f, 0.f, 0.f};
            acc[r][c] = z;
        }

    for (int k0 = 0; k0 < K; k0 += 32) {
        #pragma unroll
        for (int cc = 0; cc < 2; cc++) {
            const int row = cc * 64 + wv * 16 + lrow;
            const bf16* ga = A + (size_t)(m0 + row) * K + k0 + lk;
            __builtin_amdgcn_global_load_lds(
                (const __attribute__((address_space(1))) void*)ga,
                (__attribute__((address_space(3))) void*)&As[(cc * 64 + wv * 16) * 32],
                16, 0, 0);
            const bf16* gb = Bt + (size_t)(n0 + row) * K + k0 + lk;
            __builtin_amdgcn_global_load_lds(
                (const __attribute__((address_space(1))) void*)gb,
                (__attribute__((address_space(3))) void*)&Bs[(cc * 64 + wv * 16) * 32],
                16, 0, 0);
        }
        __syncthreads();
        b8v af[4], bfr[4];
        #pragma unroll
        for (int r = 0; r < 4; r++)
            af[r] = *(const b8v*)&As[(wm * 64 + r * 16 + lm) * 32 + quad * 8];
        #pragma unroll
        for (int c = 0; c < 4; c++)
            bfr[c] = *(const b8v*)&Bs[(wn * 64 + c * 16 + lm) * 32 + quad * 8];
        #pragma unroll
        for (int r = 0; r < 4; r++)
            #pragma unroll
            for (int c = 0; c < 4; c++)
                acc[r][c] = MFMA16(af[r], bfr[c], acc[r][c]);
        __syncthreads();
    }

    #pragma unroll
    for (int r = 0; r < 4; r++) {
        const int mbase = m0 + wm * 64 + r * 16 + quad * 4;
        #pragma unroll
        for (int c = 0; c < 4; c++) {
            const int n = n0 + wn * 64 + c * 16 + lm;
            #pragma unroll
            for (int reg = 0; reg < 4; reg++) {
                const int m = mbase + reg;
                float v = acc[r][c][reg];
                if (MODE == 1) {
                    v += bias[n];
                    v = fmaxf(v, 0.f);
                    outb[(size_t)m * N + n] = f2b(v);
                } else {  // MODE 4: QKV
                    if (n < 1024) {
                        qkvb[(size_t)m * 1024 + n] = f2b(v);
                    } else {
                        vt[((size_t)(m >> 11) * 512 + (n - 1024)) * T_ + (m & (T_ - 1))] =
                            f2b(v);
                    }
                }
            }
        }
    }
}

// ---------------- MFMA GEMM (512 thr): for small-grid GEMMs (Wo, W2) ----------------
// 128x128 tile, BK=32, 8 waves (2 m x 4 n), each wave 64x32: 4x2 mfma tiles.
// 2 waves/SIMD at 1 block/CU (these GEMMs have only 256 blocks).
// MODE 2: +bias +fp32 res -> bf16.  MODE 3: +bias +bf16 res -> fp32.
template <int MODE>
__global__ __launch_bounds__(512) void mfma_gemm2(const bf16* __restrict__ A,
                                                  const bf16* __restrict__ Bt,
                                                  const float* __restrict__ bias,
                                                  const float* __restrict__ resf,
                                                  const bf16* __restrict__ resb,
                                                  bf16* __restrict__ outb,
                                                  float* __restrict__ outf,
                                                  int M, int N, int K) {
    __shared__ short As[128 * 32];
    __shared__ short Bs[128 * 32];
    const int tid = threadIdx.x;
    const int lane = tid & 63, wv = tid >> 6;       // 8 waves
    const int wm = wv >> 2, wn = wv & 3;            // 2 x 4
    const int m0 = blockIdx.x * 128, n0 = blockIdx.y * 128;
    const int lm = lane & 15, quad = lane >> 4;

    f32x4 acc[4][2];
    #pragma unroll
    for (int r = 0; r < 4; r++)
        #pragma unroll
        for (int c = 0; c < 2; c++) {
            f32x4 z = {0.f, 0.f, 0.f, 0.f};
            acc[r][c] = z;
        }

    for (int k0 = 0; k0 < K; k0 += 32) {
        // 512 threads x 16B = one full 128x32 bf16 panel per operand.
        // wave wv covers rows wv*16..wv*16+15 (wave-uniform LDS base + lane*16).
        const int row = wv * 16 + (lane >> 2);
        const int lk = (lane & 3) * 8;
        const bf16* ga = A + (size_t)(m0 + row) * K + k0 + lk;
        __builtin_amdgcn_global_load_lds(
            (const __attribute__((address_space(1))) void*)ga,
            (__attribute__((address_space(3))) void*)&As[(wv * 16) * 32],
            16, 0, 0);
        const bf16* gb = Bt + (size_t)(n0 + row) * K + k0 + lk;
        __builtin_amdgcn_global_load_lds(
            (const __attribute__((address_space(1))) void*)gb,
            (__attribute__((address_space(3))) void*)&Bs[(wv * 16) * 32],
            16, 0, 0);
        __syncthreads();
        b8v af[4], bfr[2];
        #pragma unroll
        for (int r = 0; r < 4; r++)
            af[r] = *(const b8v*)&As[(wm * 64 + r * 16 + lm) * 32 + quad * 8];
        #pragma unroll
        for (int c = 0; c < 2; c++)
            bfr[c] = *(const b8v*)&Bs[(wn * 32 + c * 16 + lm) * 32 + quad * 8];
        #pragma unroll
        for (int r = 0; r < 4; r++)
            #pragma unroll
            for (int c = 0; c < 2; c++)
                acc[r][c] = MFMA16(af[r], bfr[c], acc[r][c]);
        __syncthreads();
    }

    #pragma unroll
    for (int r = 0; r < 4; r++) {
        const int mbase = m0 + wm * 64 + r * 16 + quad * 4;
        #pragma unroll
        for (int c = 0; c < 2; c++) {
            const int n = n0 + wn * 32 + c * 16 + lm;
            #pragma unroll
            for (int reg = 0; reg < 4; reg++) {
                const int m = mbase + reg;
                float v = acc[r][c][reg];
                if (MODE == 2) {
                    v += bias[n] + resf[(size_t)m * N + n];
                    outb[(size_t)m * N + n] = f2b(v);
                } else {  // MODE 3
                    v += bias[n] + b2f(resb[(size_t)m * N + n]);
                    outf[(size_t)m * N + n] = v;
                }
            }
        }
    }
}

// ---------------- Pass 1: Lr[s] = 1 / sum_{t>=s} exp(sc*q_t.k_s) ----------------
__global__ __launch_bounds__(512) void colsum_mfma(const bf16* __restrict__ qkv,
                                                   float* __restrict__ Lr) {
    __shared__ short Ks[128 * 72];
    __shared__ short Qs[2][128 * 72];
    __shared__ float red[8][128];
    const int tid = threadIdx.x, lane = tid & 63, wv = tid >> 6;
    const int lm = lane & 15, quad = lane >> 4;
    const int bh = blockIdx.x, bb = bh >> 3, hh = bh & 7;
    const bf16* qbase = qkv + (size_t)bb * T_ * 1024 + hh * 64;
    const bf16* kbase = qbase + 512;
    const int rA = tid >> 3, rB = 64 + (tid >> 3), ch = tid & 7;
    for (int half = 0; half < 2; half++) {
        const int strip = half ? 15 - (int)blockIdx.y : (int)blockIdx.y;
        const int s0 = strip * 128;
        *(s8v*)&Ks[rA * 72 + ch * 8] =
            *(const s8v*)(kbase + (size_t)(s0 + rA) * 1024 + ch * 8);
        *(s8v*)&Ks[rB * 72 + ch * 8] =
            *(const s8v*)(kbase + (size_t)(s0 + rB) * 1024 + ch * 8);
        s8v qrA = *(const s8v*)(qbase + (size_t)(s0 + rA) * 1024 + ch * 8);
        s8v qrB = *(const s8v*)(qbase + (size_t)(s0 + rB) * 1024 + ch * 8);
        float csum[8] = {};
        const int niter = (T_ - s0) / 128;
        for (int it = 0; it < niter; it++) {
            const int buf = it & 1;
            *(s8v*)&Qs[buf][rA * 72 + ch * 8] = qrA;
            *(s8v*)&Qs[buf][rB * 72 + ch * 8] = qrB;
            __syncthreads();
            if (it + 1 < niter) {
                const int t1 = s0 + (it + 1) * 128;
                qrA = *(const s8v*)(qbase + (size_t)(t1 + rA) * 1024 + ch * 8);
                qrB = *(const s8v*)(qbase + (size_t)(t1 + rB) * 1024 + ch * 8);
            }
            const int t0 = s0 + it * 128;
            b8v aq0 = *(const b8v*)&Qs[buf][(wv * 16 + lm) * 72 + quad * 8];
            b8v aq1 = *(const b8v*)&Qs[buf][(wv * 16 + lm) * 72 + 32 + quad * 8];
            #pragma unroll
            for (int c = 0; c < 8; c++) {
                b8v bk0 = *(const b8v*)&Ks[(c * 16 + lm) * 72 + quad * 8];
                b8v bk1 = *(const b8v*)&Ks[(c * 16 + lm) * 72 + 32 + quad * 8];
                f32x4 S = {0.f, 0.f, 0.f, 0.f};
                S = MFMA16(aq0, bk0, S);
                S = MFMA16(aq1, bk1, S);
                const int s = s0 + c * 16 + lm;
                #pragma unroll
                for (int reg = 0; reg < 4; reg++) {
                    int t = t0 + wv * 16 + quad * 4 + reg;
                    if (t >= s) csum[c] += __expf(S[reg] * SCALE_);
                }
            }
        }
        __syncthreads();
        #pragma unroll
        for (int c = 0; c < 8; c++) {
            float v = csum[c];
            v += __shfl_xor(v, 16);
            v += __shfl_xor(v, 32);
            if (lane < 16) red[wv][c * 16 + lane] = v;
        }
        __syncthreads();
        if (tid < 128) {
            float s = 0.f;
            #pragma unroll
            for (int i = 0; i < 8; i++) s += red[i][tid];
            Lr[(size_t)bh * T_ + s0 + tid] = 1.0f / s;
        }
        __syncthreads();
    }
}

// ---------------- Pass 2: out_t = sum_{s<=t} exp(sc*q_t.k_s) * (v_s * Lr_s) ----------------
__global__ __launch_bounds__(512) void attnout_mfma(const bf16* __restrict__ qkv,
                                                    const bf16* __restrict__ vt,
                                                    const float* __restrict__ Lr,
                                                    bf16* __restrict__ attn) {
    __shared__ short Qs[128 * 72];
    __shared__ short Ps[128 * 72];
    __shared__ short Ks[2][64 * 72];
    __shared__ short Vt[2][64 * 72];
    const int tid = threadIdx.x, lane = tid & 63, wv = tid >> 6;
    const int lm = lane & 15, quad = lane >> 4;
    const int bh = blockIdx.x, bb = bh >> 3, hh = bh & 7;
    const bf16* qbase = qkv + (size_t)bb * T_ * 1024 + hh * 64;
    const bf16* kbase = qbase + 512;
    const bf16* vtb = vt + ((size_t)bb * 512 + hh * 64) * T_;
    const float* Lrb = Lr + (size_t)bh * T_;
    const int r = tid >> 3, ch = tid & 7;
    for (int half = 0; half < 2; half++) {
        const int strip = half ? 15 - (int)blockIdx.y : (int)blockIdx.y;
        const int tb = strip * 128;
        #pragma unroll
        for (int cc = 0; cc < 2; cc++) {
            int idx = cc * 512 + tid, qr = idx >> 3, qc = idx & 7;
            *(s8v*)&Qs[qr * 72 + qc * 8] =
                *(const s8v*)(qbase + (size_t)(tb + qr) * 1024 + qc * 8);
        }
        s8v kreg = *(const s8v*)(kbase + (size_t)r * 1024 + ch * 8);
        s8v vreg = *(const s8v*)(vtb + (size_t)r * T_ + ch * 8);
        float4 lr0 = *(const float4*)(Lrb + ch * 8);
        float4 lr1 = *(const float4*)(Lrb + ch * 8 + 4);
        f32x4 o[4];
        #pragma unroll
        for (int c = 0; c < 4; c++) {
            f32x4 z = {0.f, 0.f, 0.f, 0.f};
            o[c] = z;
        }
        const int niter = (tb + 128) / 64;
        for (int it = 0; it < niter; it++) {
            const int s0 = it * 64, buf = it & 1;
            s8v vs;
            vs[0] = f2bs(s2f(vreg[0]) * lr0.x);
            vs[1] = f2bs(s2f(vreg[1]) * lr0.y);
            vs[2] = f2bs(s2f(vreg[2]) * lr0.z);
            vs[3] = f2bs(s2f(vreg[3]) * lr0.w);
            vs[4] = f2bs(s2f(vreg[4]) * lr1.x);
            vs[5] = f2bs(s2f(vreg[5]) * lr1.y);
            vs[6] = f2bs(s2f(vreg[6]) * lr1.z);
            vs[7] = f2bs(s2f(vreg[7]) * lr1.w);
            *(s8v*)&Ks[buf][r * 72 + ch * 8] = kreg;
            *(s8v*)&Vt[buf][r * 72 + ch * 8] = vs;
            __syncthreads();
            if (it + 1 < niter) {
                const int s1 = s0 + 64;
                kreg = *(const s8v*)(kbase + (size_t)(s1 + r) * 1024 + ch * 8);
                vreg = *(const s8v*)(vtb + (size_t)r * T_ + s1 + ch * 8);
                lr0 = *(const float4*)(Lrb + s1 + ch * 8);
                lr1 = *(const float4*)(Lrb + s1 + ch * 8 + 4);
            }
            b8v bq0 = *(const b8v*)&Qs[(wv * 16 + lm) * 72 + quad * 8];
            b8v bq1 = *(const b8v*)&Qs[(wv * 16 + lm) * 72 + 32 + quad * 8];
            const int t = tb + wv * 16 + lm;
            #pragma unroll
            for (int c = 0; c < 4; c++) {
                b8v ak0 = *(const b8v*)&Ks[buf][(c * 16 + lm) * 72 + quad * 8];
                b8v ak1 = *(const b8v*)&Ks[buf][(c * 16 + lm) * 72 + 32 + quad * 8];
                f32x4 S = {0.f, 0.f, 0.f, 0.f};
                S = MFMA16(ak0, bq0, S);
                S = MFMA16(ak1, bq1, S);
                s4v p;
                #pragma unroll
                for (int reg = 0; reg < 4; reg++) {
                    int s = s0 + c * 16 + quad * 4 + reg;
                    float e = (t >= s) ? __expf(S[reg] * SCALE_) : 0.f;
                    p[reg] = f2bs(e);
                }
                *(s4v*)&Ps[(wv * 16 + lm) * 72 + c * 16 + quad * 4] = p;
            }
            b8v ap0 = *(const b8v*)&Ps[(wv * 16 + lm) * 72 + quad * 8];
            b8v ap1 = *(const b8v*)&Ps[(wv * 16 + lm) * 72 + 32 + quad * 8];
            #pragma unroll
            for (int c = 0; c < 4; c++) {
                b8v bv0 = *(const b8v*)&Vt[buf][(c * 16 + lm) * 72 + quad * 8];
                b8v bv1 = *(const b8v*)&Vt[buf][(c * 16 + lm) * 72 + 32 + quad * 8];
                o[c] = MFMA16(ap0, bv0, o[c]);
                o[c] = MFMA16(ap1, bv1, o[c]);
            }
        }
        #pragma unroll
        for (int c = 0; c < 4; c++)
            #pragma unroll
            for (int reg = 0; reg < 4; reg++)
                attn[(size_t)(bb * T_ + tb + wv * 16 + quad * 4 + reg) * C_ + hh * 64 +
                     c * 16 + lm] = f2b(o[c][reg]);
        __syncthreads();
    }
}

extern "C" void kernel_launch(void* const* d_in, const int* in_sizes, int n_in,
                              void* d_out, int out_size, void* d_ws, size_t ws_size,
                              hipStream_t stream) {
    const float* x   = (const float*)d_in[0];
    const float* Wq  = (const float*)d_in[1];
    const float* Wk  = (const float*)d_in[2];
    const float* Wv  = (const float*)d_in[3];
    const float* Wo  = (const float*)d_in[4];
    const float* bo  = (const float*)d_in[5];
    const float* W1  = (const float*)d_in[6];
    const float* b1  = (const float*)d_in[7];
    const float* W2  = (const float*)d_in[8];
    const float* b2  = (const float*)d_in[9];
    const float* g1  = (const float*)d_in[10];
    const float* be1 = (const float*)d_in[11];
    const float* g2  = (const float*)d_in[12];
    const float* be2 = (const float*)d_in[13];
    float* out = (float*)d_out;

    // Workspace (~62 MB). Region A (32 MB) is time-multiplexed:
    //   [qkvb 16MB | attn 8MB | hbuf 8MB]  then reused whole as ff1 (32MB).
    char* w = (char*)d_ws;
    auto alloc = [&](size_t bytes) -> void* {
        void* p = (void*)w;
        w += (bytes + 255) & ~(size_t)255;
        return p;
    };
    bf16* regionA = (bf16*)alloc((size_t)BT_ * 2048 * sizeof(bf16));  // 32MB
    bf16* qkvb = regionA;                                // [BT][1024] (q|k)
    bf16* attn = regionA + (size_t)BT_ * 1024;           // [BT][512]
    bf16* hbuf = regionA + (size_t)BT_ * 1536;           // [BT][512]
    bf16* ff1  = regionA;                                // [BT][2048]
    bf16* x1     = (bf16*)alloc((size_t)BT_ * C_ * sizeof(bf16));
    bf16* h2     = (bf16*)alloc((size_t)BT_ * C_ * sizeof(bf16));
    bf16* vt     = (bf16*)alloc((size_t)B_ * 512 * T_ * sizeof(bf16));   // [B][H*D][T]
    bf16* WqkvT  = (bf16*)alloc((size_t)1536 * C_ * sizeof(bf16));       // [1536][512]
    bf16* WoT    = (bf16*)alloc((size_t)C_ * C_ * sizeof(bf16));
    bf16* W1T    = (bf16*)alloc((size_t)C4_ * C_ * sizeof(bf16));        // [2048][512]
    bf16* W2T    = (bf16*)alloc((size_t)C_ * C4_ * sizeof(bf16));        // [512][2048]
    float* Lr    = (float*)alloc((size_t)B_ * H_ * T_ * sizeof(float));

    // All weight transposes (fp32 -> bf16 [N][K]) in one launch
    transpose_all<<<768, 256, 0, stream>>>(Wq, Wk, Wv, Wo, W1, W2,
                                           WqkvT, WoT, W1T, W2T);
    // 1. h = LN(x)
    ln_kernel<float><<<BT_, 256, 0, stream>>>(x, g1, be1, hbuf);
    // 2. QKV GEMM: [8192,1536,512]; q,k -> qkvb, v -> vt (transposed)
    mfma_gemm<4><<<dim3(BT_ / 128, 1536 / 128), 256, 0, stream>>>(
        hbuf, WqkvT, nullptr, nullptr, qkvb, vt, BT_, 1536, C_);
    // 3. column-sum reciprocals (XCD-swizzled grid)
    colsum_mfma<<<dim3(B_ * H_, 8), 512, 0, stream>>>(qkvb, Lr);
    // 4. attention output (XCD-swizzled grid)
    attnout_mfma<<<dim3(B_ * H_, 8), 512, 0, stream>>>(qkvb, vt, Lr, attn);
    // 5. x1 = x + attn @ Wo + bo   (512-thread variant: 256-block grid)
    mfma_gemm2<2><<<dim3(BT_ / 128, C_ / 128), 512, 0, stream>>>(
        attn, WoT, bo, x, nullptr, x1, nullptr, BT_, C_, C_);
    // 6. h2 = LN(x1)
    ln_kernel<bf16><<<BT_, 256, 0, stream>>>(x1, g2, be2, h2);
    // 7. ff1 = relu(h2 @ W1 + b1)
    mfma_gemm<1><<<dim3(BT_ / 128, C4_ / 128), 256, 0, stream>>>(
        h2, W1T, b1, ff1, nullptr, nullptr, BT_, C4_, C_);
    // 8. out = x1 + ff1 @ W2 + b2  (512-thread variant: 256-block grid)
    mfma_gemm2<3><<<dim3(BT_ / 128, C_ / 128), 512, 0, stream>>>(
        ff1, W2T, b2, nullptr, x1, nullptr, out, BT_, C_, C4_);
}

// Round 8
// 285.641 us; speedup vs baseline: 12.7953x; 1.0263x over previous
//
#include <hip/hip_runtime.h>
#include <hip/hip_bf16.h>

// Block_4776003633552: transformer block, B=4 T=2048 C=512 H=8 D=64. fp32 I/O.
// Reference quirks: scale = C^-0.5; softmax over QUERY axis (axis=-2) =>
//   out_t = sum_{s<=t} exp(sc*q_t.k_s) * v_s / L_s,  L_s = sum_{t>=s} exp(sc*q_t.k_s).
// Round 8 (= round 7 retry, compile fix): pk2 uses __builtin_memcpy instead of
// bit_cast (__hip_bfloat162 is not trivially copyable on this ROCm).
// W2 split-K x2 (512 blocks -> 2/CU); attention causal mask diagonal-only;
// packed bf16 cvts via v_cvt_pk_bf16_f32.

typedef __hip_bfloat16 bf16;
typedef __bf16 b8v __attribute__((ext_vector_type(8)));   // MFMA A/B fragment (8 bf16)
typedef float  f32x4 __attribute__((ext_vector_type(4))); // MFMA C/D fragment
typedef short  s8v  __attribute__((ext_vector_type(8)));  // 16B bf16 copy chunk
typedef short  s4v  __attribute__((ext_vector_type(4)));  // 8B packed chunk

#define B_   4
#define T_   2048
#define C_   512
#define H_   8
#define D_   64
#define BT_  (B_ * T_)
#define C4_  (4 * C_)
#define EPS_ 1e-5f
#define SCALE_ 0.04419417382415922f  // 1/sqrt(512)

#define MFMA16(a, b, c) __builtin_amdgcn_mfma_f32_16x16x32_bf16(a, b, c, 0, 0, 0)

static __device__ __forceinline__ float b2f(bf16 x) { return __bfloat162float(x); }
static __device__ __forceinline__ bf16  f2b(float x) { return __float2bfloat16(x); }
static __device__ __forceinline__ float s2f(short x) {
    return b2f(__builtin_bit_cast(bf16, x));
}
// packed 2xfp32 -> 2xbf16 (v_cvt_pk_bf16_f32); memcpy because __hip_bfloat162
// is not trivially copyable (bit_cast rejected).
static __device__ __forceinline__ unsigned int pk2(float a, float b) {
    float2 f;
    f.x = a;
    f.y = b;
    __hip_bfloat162 h = __float22bfloat162_rn(f);
    unsigned int u;
    __builtin_memcpy(&u, &h, 4);
    return u;
}

// ---------------- LayerNorm over C=512, one block per row ----------------
static __device__ __forceinline__ float ldv(const float* p) { return *p; }
static __device__ __forceinline__ float ldv(const bf16* p)  { return b2f(*p); }

template <typename TIN>
__global__ __launch_bounds__(256) void ln_kernel(const TIN* __restrict__ x,
                                                 const float* __restrict__ g,
                                                 const float* __restrict__ be,
                                                 bf16* __restrict__ out) {
    const int row = blockIdx.x;
    const int tid = threadIdx.x;
    const TIN* xr = x + (size_t)row * C_;
    float v0 = ldv(xr + tid * 2);
    float v1 = ldv(xr + tid * 2 + 1);
    float s = v0 + v1;
    float sq = v0 * v0 + v1 * v1;
    #pragma unroll
    for (int o = 32; o > 0; o >>= 1) {
        s += __shfl_down(s, o);
        sq += __shfl_down(sq, o);
    }
    __shared__ float ws[8], wsq[8];
    const int wid = tid >> 6, lane = tid & 63;
    if (lane == 0) { ws[wid] = s; wsq[wid] = sq; }
    __syncthreads();
    if (tid == 0) {
        float ts = 0.f, tq = 0.f;
        #pragma unroll
        for (int i = 0; i < 4; i++) { ts += ws[i]; tq += wsq[i]; }
        float mu = ts * (1.f / C_);
        float var = tq * (1.f / C_) - mu * mu;
        ws[4] = mu;
        wsq[4] = rsqrtf(var + EPS_);
    }
    __syncthreads();
    const float mu = ws[4], rstd = wsq[4];
    bf16* orow = out + (size_t)row * C_;
    orow[tid * 2]     = f2b((v0 - mu) * rstd * g[tid * 2]     + be[tid * 2]);
    orow[tid * 2 + 1] = f2b((v1 - mu) * rstd * g[tid * 2 + 1] + be[tid * 2 + 1]);
}

// ---------------- All weight transposes in one launch (768 blocks) ----------------
__global__ __launch_bounds__(256) void transpose_all(const float* __restrict__ Wq,
                                                     const float* __restrict__ Wk,
                                                     const float* __restrict__ Wv,
                                                     const float* __restrict__ Wo,
                                                     const float* __restrict__ W1,
                                                     const float* __restrict__ W2,
                                                     bf16* __restrict__ WqkvT,
                                                     bf16* __restrict__ WoT,
                                                     bf16* __restrict__ W1T,
                                                     bf16* __restrict__ W2T) {
    __shared__ float Ts[64][65];
    const int tid = threadIdx.x;
    const int id = blockIdx.x;
    if (id < 192) {
        const int sub = id / 64, rem = id % 64;
        const int x = rem & 7, hh = rem >> 3;
        const float* src = (sub == 0 ? Wq : sub == 1 ? Wk : Wv) + (size_t)hh * C_ * D_;
        bf16* dst = WqkvT + (size_t)sub * 512 * C_;
        const int c0 = x * 64;
        #pragma unroll
        for (int p = 0; p < 16; p++) {
            int idx = p * 256 + tid, i = idx >> 6, j = idx & 63;
            Ts[i][j] = src[(size_t)(c0 + i) * D_ + j];
        }
        __syncthreads();
        #pragma unroll
        for (int p = 0; p < 16; p++) {
            int idx = p * 256 + tid, j = idx >> 6, i = idx & 63;
            dst[(size_t)(hh * 64 + j) * C_ + c0 + i] = f2b(Ts[i][j]);
        }
    } else {
        const float* src;
        bf16* dst;
        int r0, c0, R, Cc;
        if (id < 256) {
            int rem = id - 192;
            src = Wo; dst = WoT; R = 512; Cc = 512;
            r0 = (rem & 7) * 64; c0 = (rem >> 3) * 64;
        } else if (id < 512) {
            int rem = id - 256;
            src = W1; dst = W1T; R = 512; Cc = 2048;
            r0 = (rem & 7) * 64; c0 = (rem >> 3) * 64;
        } else {
            int rem = id - 512;
            src = W2; dst = W2T; R = 2048; Cc = 512;
            r0 = (rem & 31) * 64; c0 = (rem >> 5) * 64;
        }
        #pragma unroll
        for (int p = 0; p < 16; p++) {
            int idx = p * 256 + tid, i = idx >> 6, j = idx & 63;
            Ts[i][j] = src[(size_t)(r0 + i) * Cc + c0 + j];
        }
        __syncthreads();
        #pragma unroll
        for (int p = 0; p < 16; p++) {
            int idx = p * 256 + tid, j = idx >> 6, i = idx & 63;
            dst[(size_t)(c0 + j) * R + r0 + i] = f2b(Ts[i][j]);
        }
    }
}

// ---------------- MFMA GEMM (256 thr): C[M,N] = A[M,K] @ Bt[N,K]^T ----------------
// 128x128 tile, BK=32, 4 waves (2x2 of 64x64), 4x4 mfma tiles/wave.
// MODE 1: +bias +relu -> bf16.  MODE 4: QKV split (q,k -> qkvb; v -> vt).
template <int MODE>
__global__ __launch_bounds__(256) void mfma_gemm(const bf16* __restrict__ A,
                                                 const bf16* __restrict__ Bt,
                                                 const float* __restrict__ bias,
                                                 bf16* __restrict__ outb,
                                                 bf16* __restrict__ qkvb,
                                                 bf16* __restrict__ vt,
                                                 int M, int N, int K) {
    __shared__ short As[128 * 32];
    __shared__ short Bs[128 * 32];
    const int tid = threadIdx.x;
    const int lane = tid & 63, wv = tid >> 6;
    const int wm = wv >> 1, wn = wv & 1;
    const int m0 = blockIdx.x * 128, n0 = blockIdx.y * 128;
    const int lrow = lane >> 2, lk = (lane & 3) * 8;
    const int lm = lane & 15, quad = lane >> 4;

    f32x4 acc[4][4];
    #pragma unroll
    for (int r = 0; r < 4; r++)
        #pragma unroll
        for (int c = 0; c < 4; c++) {
            f32x4 z = {0.f, 0.f, 0.f, 0.f};
            acc[r][c] = z;
        }

    for (int k0 = 0; k0 < K; k0 += 32) {
        #pragma unroll
        for (int cc = 0; cc < 2; cc++) {
            const int row = cc * 64 + wv * 16 + lrow;
            const bf16* ga = A + (size_t)(m0 + row) * K + k0 + lk;
            __builtin_amdgcn_global_load_lds(
                (const __attribute__((address_space(1))) void*)ga,
                (__attribute__((address_space(3))) void*)&As[(cc * 64 + wv * 16) * 32],
                16, 0, 0);
            const bf16* gb = Bt + (size_t)(n0 + row) * K + k0 + lk;
            __builtin_amdgcn_global_load_lds(
                (const __attribute__((address_space(1))) void*)gb,
                (__attribute__((address_space(3))) void*)&Bs[(cc * 64 + wv * 16) * 32],
                16, 0, 0);
        }
        __syncthreads();
        b8v af[4], bfr[4];
        #pragma unroll
        for (int r = 0; r < 4; r++)
            af[r] = *(const b8v*)&As[(wm * 64 + r * 16 + lm) * 32 + quad * 8];
        #pragma unroll
        for (int c = 0; c < 4; c++)
            bfr[c] = *(const b8v*)&Bs[(wn * 64 + c * 16 + lm) * 32 + quad * 8];
        #pragma unroll
        for (int r = 0; r < 4; r++)
            #pragma unroll
            for (int c = 0; c < 4; c++)
                acc[r][c] = MFMA16(af[r], bfr[c], acc[r][c]);
        __syncthreads();
    }

    #pragma unroll
    for (int r = 0; r < 4; r++) {
        const int mbase = m0 + wm * 64 + r * 16 + quad * 4;
        #pragma unroll
        for (int c = 0; c < 4; c++) {
            const int n = n0 + wn * 64 + c * 16 + lm;
            #pragma unroll
            for (int reg = 0; reg < 4; reg++) {
                const int m = mbase + reg;
                float v = acc[r][c][reg];
                if (MODE == 1) {
                    v += bias[n];
                    v = fmaxf(v, 0.f);
                    outb[(size_t)m * N + n] = f2b(v);
                } else {  // MODE 4: QKV
                    if (n < 1024) {
                        qkvb[(size_t)m * 1024 + n] = f2b(v);
                    } else {
                        vt[((size_t)(m >> 11) * 512 + (n - 1024)) * T_ + (m & (T_ - 1))] =
                            f2b(v);
                    }
                }
            }
        }
    }
}

// ---------------- Split-K MFMA GEMM: partial[z] = A[:, zKh:(z+1)Kh] @ Bt^T ----------------
// Same 128x128 tile; grid (M/128, N/128, 2) -> 2 blocks/CU co-residency.
// Partials in bf16 (reused dead ws regions).
__global__ __launch_bounds__(256) void mfma_gemm_sk(const bf16* __restrict__ A,
                                                    const bf16* __restrict__ Bt,
                                                    bf16* __restrict__ part,
                                                    int M, int N, int K, int Khalf) {
    __shared__ short As[128 * 32];
    __shared__ short Bs[128 * 32];
    const int tid = threadIdx.x;
    const int lane = tid & 63, wv = tid >> 6;
    const int wm = wv >> 1, wn = wv & 1;
    const int m0 = blockIdx.x * 128, n0 = blockIdx.y * 128;
    const int kbase = blockIdx.z * Khalf;
    const int lrow = lane >> 2, lk = (lane & 3) * 8;
    const int lm = lane & 15, quad = lane >> 4;

    f32x4 acc[4][4];
    #pragma unroll
    for (int r = 0; r < 4; r++)
        #pragma unroll
        for (int c = 0; c < 4; c++) {
            f32x4 z = {0.f, 0.f, 0.f, 0.f};
            acc[r][c] = z;
        }

    for (int kk = 0; kk < Khalf; kk += 32) {
        const int k0 = kbase + kk;
        #pragma unroll
        for (int cc = 0; cc < 2; cc++) {
            const int row = cc * 64 + wv * 16 + lrow;
            const bf16* ga = A + (size_t)(m0 + row) * K + k0 + lk;
            __builtin_amdgcn_global_load_lds(
                (const __attribute__((address_space(1))) void*)ga,
                (__attribute__((address_space(3))) void*)&As[(cc * 64 + wv * 16) * 32],
                16, 0, 0);
            const bf16* gb = Bt + (size_t)(n0 + row) * K + k0 + lk;
            __builtin_amdgcn_global_load_lds(
                (const __attribute__((address_space(1))) void*)gb,
                (__attribute__((address_space(3))) void*)&Bs[(cc * 64 + wv * 16) * 32],
                16, 0, 0);
        }
        __syncthreads();
        b8v af[4], bfr[4];
        #pragma unroll
        for (int r = 0; r < 4; r++)
            af[r] = *(const b8v*)&As[(wm * 64 + r * 16 + lm) * 32 + quad * 8];
        #pragma unroll
        for (int c = 0; c < 4; c++)
            bfr[c] = *(const b8v*)&Bs[(wn * 64 + c * 16 + lm) * 32 + quad * 8];
        #pragma unroll
        for (int r = 0; r < 4; r++)
            #pragma unroll
            for (int c = 0; c < 4; c++)
                acc[r][c] = MFMA16(af[r], bfr[c], acc[r][c]);
        __syncthreads();
    }

    bf16* pz = part + (size_t)blockIdx.z * M * N;
    #pragma unroll
    for (int r = 0; r < 4; r++) {
        const int mbase = m0 + wm * 64 + r * 16 + quad * 4;
        #pragma unroll
        for (int c = 0; c < 4; c++) {
            const int n = n0 + wn * 64 + c * 16 + lm;
            #pragma unroll
            for (int reg = 0; reg < 4; reg++)
                pz[(size_t)(mbase + reg) * N + n] = f2b(acc[r][c][reg]);
        }
    }
}

// ---------------- reduce: out = p0 + p1 + bias + res (fp32 out) ----------------
__global__ __launch_bounds__(256) void reduce_w2(const bf16* __restrict__ part,
                                                 const float* __restrict__ bias,
                                                 const bf16* __restrict__ res,
                                                 float* __restrict__ out) {
    const size_t i = ((size_t)blockIdx.x * 256 + threadIdx.x) * 4;
    const int n = (int)(i & (C_ - 1));
    s4v a = *(const s4v*)(part + i);
    s4v b = *(const s4v*)(part + (size_t)BT_ * C_ + i);
    s4v rv = *(const s4v*)(res + i);
    float4 bs = *(const float4*)(bias + n);
    float4 o;
    o.x = s2f(a[0]) + s2f(b[0]) + bs.x + s2f(rv[0]);
    o.y = s2f(a[1]) + s2f(b[1]) + bs.y + s2f(rv[1]);
    o.z = s2f(a[2]) + s2f(b[2]) + bs.z + s2f(rv[2]);
    o.w = s2f(a[3]) + s2f(b[3]) + bs.w + s2f(rv[3]);
    *(float4*)(out + i) = o;
}

// ---------------- MFMA GEMM (512 thr): Wo (+bias +fp32 res -> bf16) ----------------
__global__ __launch_bounds__(512) void mfma_gemm2(const bf16* __restrict__ A,
                                                  const bf16* __restrict__ Bt,
                                                  const float* __restrict__ bias,
                                                  const float* __restrict__ resf,
                                                  bf16* __restrict__ outb,
                                                  int M, int N, int K) {
    __shared__ short As[128 * 32];
    __shared__ short Bs[128 * 32];
    const int tid = threadIdx.x;
    const int lane = tid & 63, wv = tid >> 6;       // 8 waves
    const int wm = wv >> 2, wn = wv & 3;            // 2 x 4
    const int m0 = blockIdx.x * 128, n0 = blockIdx.y * 128;
    const int lm = lane & 15, quad = lane >> 4;

    f32x4 acc[4][2];
    #pragma unroll
    for (int r = 0; r < 4; r++)
        #pragma unroll
        for (int c = 0; c < 2; c++) {
            f32x4 z = {0.f, 0.f, 0.f, 0.f};
            acc[r][c] = z;
        }

    for (int k0 = 0; k0 < K; k0 += 32) {
        const int row = wv * 16 + (lane >> 2);
        const int lk = (lane & 3) * 8;
        const bf16* ga = A + (size_t)(m0 + row) * K + k0 + lk;
        __builtin_amdgcn_global_load_lds(
            (const __attribute__((address_space(1))) void*)ga,
            (__attribute__((address_space(3))) void*)&As[(wv * 16) * 32],
            16, 0, 0);
        const bf16* gb = Bt + (size_t)(n0 + row) * K + k0 + lk;
        __builtin_amdgcn_global_load_lds(
            (const __attribute__((address_space(1))) void*)gb,
            (__attribute__((address_space(3))) void*)&Bs[(wv * 16) * 32],
            16, 0, 0);
        __syncthreads();
        b8v af[4], bfr[2];
        #pragma unroll
        for (int r = 0; r < 4; r++)
            af[r] = *(const b8v*)&As[(wm * 64 + r * 16 + lm) * 32 + quad * 8];
        #pragma unroll
        for (int c = 0; c < 2; c++)
            bfr[c] = *(const b8v*)&Bs[(wn * 32 + c * 16 + lm) * 32 + quad * 8];
        #pragma unroll
        for (int r = 0; r < 4; r++)
            #pragma unroll
            for (int c = 0; c < 2; c++)
                acc[r][c] = MFMA16(af[r], bfr[c], acc[r][c]);
        __syncthreads();
    }

    #pragma unroll
    for (int r = 0; r < 4; r++) {
        const int mbase = m0 + wm * 64 + r * 16 + quad * 4;
        #pragma unroll
        for (int c = 0; c < 2; c++) {
            const int n = n0 + wn * 32 + c * 16 + lm;
            #pragma unroll
            for (int reg = 0; reg < 4; reg++) {
                const int m = mbase + reg;
                float v = acc[r][c][reg] + bias[n] + resf[(size_t)m * N + n];
                outb[(size_t)m * N + n] = f2b(v);
            }
        }
    }
}

// ---------------- Pass 1: Lr[s] = 1 / sum_{t>=s} exp(sc*q_t.k_s) ----------------
__global__ __launch_bounds__(512) void colsum_mfma(const bf16* __restrict__ qkv,
                                                   float* __restrict__ Lr) {
    __shared__ short Ks[128 * 72];
    __shared__ short Qs[2][128 * 72];
    __shared__ float red[8][128];
    const int tid = threadIdx.x, lane = tid & 63, wv = tid >> 6;
    const int lm = lane & 15, quad = lane >> 4;
    const int bh = blockIdx.x, bb = bh >> 3, hh = bh & 7;
    const bf16* qbase = qkv + (size_t)bb * T_ * 1024 + hh * 64;
    const bf16* kbase = qbase + 512;
    const int rA = tid >> 3, rB = 64 + (tid >> 3), ch = tid & 7;
    for (int half = 0; half < 2; half++) {
        const int strip = half ? 15 - (int)blockIdx.y : (int)blockIdx.y;
        const int s0 = strip * 128;
        *(s8v*)&Ks[rA * 72 + ch * 8] =
            *(const s8v*)(kbase + (size_t)(s0 + rA) * 1024 + ch * 8);
        *(s8v*)&Ks[rB * 72 + ch * 8] =
            *(const s8v*)(kbase + (size_t)(s0 + rB) * 1024 + ch * 8);
        s8v qrA = *(const s8v*)(qbase + (size_t)(s0 + rA) * 1024 + ch * 8);
        s8v qrB = *(const s8v*)(qbase + (size_t)(s0 + rB) * 1024 + ch * 8);
        float csum[8] = {};
        const int niter = (T_ - s0) / 128;
        for (int it = 0; it < niter; it++) {
            const int buf = it & 1;
            *(s8v*)&Qs[buf][rA * 72 + ch * 8] = qrA;
            *(s8v*)&Qs[buf][rB * 72 + ch * 8] = qrB;
            __syncthreads();
            if (it + 1 < niter) {
                const int t1 = s0 + (it + 1) * 128;
                qrA = *(const s8v*)(qbase + (size_t)(t1 + rA) * 1024 + ch * 8);
                qrB = *(const s8v*)(qbase + (size_t)(t1 + rB) * 1024 + ch * 8);
            }
            const int t0 = s0 + it * 128;
            b8v aq0 = *(const b8v*)&Qs[buf][(wv * 16 + lm) * 72 + quad * 8];
            b8v aq1 = *(const b8v*)&Qs[buf][(wv * 16 + lm) * 72 + 32 + quad * 8];
            if (it == 0) {  // diagonal: causal mask needed
                #pragma unroll
                for (int c = 0; c < 8; c++) {
                    b8v bk0 = *(const b8v*)&Ks[(c * 16 + lm) * 72 + quad * 8];
                    b8v bk1 = *(const b8v*)&Ks[(c * 16 + lm) * 72 + 32 + quad * 8];
                    f32x4 S = {0.f, 0.f, 0.f, 0.f};
                    S = MFMA16(aq0, bk0, S);
                    S = MFMA16(aq1, bk1, S);
                    const int s = s0 + c * 16 + lm;
                    #pragma unroll
                    for (int reg = 0; reg < 4; reg++) {
                        int t = t0 + wv * 16 + quad * 4 + reg;
                        if (t >= s) csum[c] += __expf(S[reg] * SCALE_);
                    }
                }
            } else {  // strictly below diagonal: no mask
                #pragma unroll
                for (int c = 0; c < 8; c++) {
                    b8v bk0 = *(const b8v*)&Ks[(c * 16 + lm) * 72 + quad * 8];
                    b8v bk1 = *(const b8v*)&Ks[(c * 16 + lm) * 72 + 32 + quad * 8];
                    f32x4 S = {0.f, 0.f, 0.f, 0.f};
                    S = MFMA16(aq0, bk0, S);
                    S = MFMA16(aq1, bk1, S);
                    csum[c] += __expf(S[0] * SCALE_) + __expf(S[1] * SCALE_) +
                               __expf(S[2] * SCALE_) + __expf(S[3] * SCALE_);
                }
            }
        }
        __syncthreads();
        #pragma unroll
        for (int c = 0; c < 8; c++) {
            float v = csum[c];
            v += __shfl_xor(v, 16);
            v += __shfl_xor(v, 32);
            if (lane < 16) red[wv][c * 16 + lane] = v;
        }
        __syncthreads();
        if (tid < 128) {
            float s = 0.f;
            #pragma unroll
            for (int i = 0; i < 8; i++) s += red[i][tid];
            Lr[(size_t)bh * T_ + s0 + tid] = 1.0f / s;
        }
        __syncthreads();
    }
}

// ---------------- Pass 2: out_t = sum_{s<=t} exp(sc*q_t.k_s) * (v_s * Lr_s) ----------------
__global__ __launch_bounds__(512) void attnout_mfma(const bf16* __restrict__ qkv,
                                                    const bf16* __restrict__ vt,
                                                    const float* __restrict__ Lr,
                                                    bf16* __restrict__ attn) {
    __shared__ short Qs[128 * 72];
    __shared__ short Ps[128 * 72];
    __shared__ short Ks[2][64 * 72];
    __shared__ short Vt[2][64 * 72];
    const int tid = threadIdx.x, lane = tid & 63, wv = tid >> 6;
    const int lm = lane & 15, quad = lane >> 4;
    const int bh = blockIdx.x, bb = bh >> 3, hh = bh & 7;
    const bf16* qbase = qkv + (size_t)bb * T_ * 1024 + hh * 64;
    const bf16* kbase = qbase + 512;
    const bf16* vtb = vt + ((size_t)bb * 512 + hh * 64) * T_;
    const float* Lrb = Lr + (size_t)bh * T_;
    const int r = tid >> 3, ch = tid & 7;
    for (int half = 0; half < 2; half++) {
        const int strip = half ? 15 - (int)blockIdx.y : (int)blockIdx.y;
        const int tb = strip * 128;
        #pragma unroll
        for (int cc = 0; cc < 2; cc++) {
            int idx = cc * 512 + tid, qr = idx >> 3, qc = idx & 7;
            *(s8v*)&Qs[qr * 72 + qc * 8] =
                *(const s8v*)(qbase + (size_t)(tb + qr) * 1024 + qc * 8);
        }
        s8v kreg = *(const s8v*)(kbase + (size_t)r * 1024 + ch * 8);
        s8v vreg = *(const s8v*)(vtb + (size_t)r * T_ + ch * 8);
        float4 lr0 = *(const float4*)(Lrb + ch * 8);
        float4 lr1 = *(const float4*)(Lrb + ch * 8 + 4);
        f32x4 o[4];
        #pragma unroll
        for (int c = 0; c < 4; c++) {
            f32x4 z = {0.f, 0.f, 0.f, 0.f};
            o[c] = z;
        }
        const int niter = (tb + 128) / 64;
        for (int it = 0; it < niter; it++) {
            const int s0 = it * 64, buf = it & 1;
            // scale V by 1/L (packed cvt) and commit staged tile
            uint4 vs;
            vs.x = pk2(s2f(vreg[0]) * lr0.x, s2f(vreg[1]) * lr0.y);
            vs.y = pk2(s2f(vreg[2]) * lr0.z, s2f(vreg[3]) * lr0.w);
            vs.z = pk2(s2f(vreg[4]) * lr1.x, s2f(vreg[5]) * lr1.y);
            vs.w = pk2(s2f(vreg[6]) * lr1.z, s2f(vreg[7]) * lr1.w);
            *(s8v*)&Ks[buf][r * 72 + ch * 8] = kreg;
            *(uint4*)&Vt[buf][r * 72 + ch * 8] = vs;
            __syncthreads();
            if (it + 1 < niter) {
                const int s1 = s0 + 64;
                kreg = *(const s8v*)(kbase + (size_t)(s1 + r) * 1024 + ch * 8);
                vreg = *(const s8v*)(vtb + (size_t)r * T_ + s1 + ch * 8);
                lr0 = *(const float4*)(Lrb + s1 + ch * 8);
                lr1 = *(const float4*)(Lrb + s1 + ch * 8 + 4);
            }
            // S^T = K . Q^T : D[row=s local][col=t local]
            b8v bq0 = *(const b8v*)&Qs[(wv * 16 + lm) * 72 + quad * 8];
            b8v bq1 = *(const b8v*)&Qs[(wv * 16 + lm) * 72 + 32 + quad * 8];
            const int t = tb + wv * 16 + lm;
            const bool masked = (s0 >= tb);  // only diagonal-region tiles
            #pragma unroll
            for (int c = 0; c < 4; c++) {
                b8v ak0 = *(const b8v*)&Ks[buf][(c * 16 + lm) * 72 + quad * 8];
                b8v ak1 = *(const b8v*)&Ks[buf][(c * 16 + lm) * 72 + 32 + quad * 8];
                f32x4 S = {0.f, 0.f, 0.f, 0.f};
                S = MFMA16(ak0, bq0, S);
                S = MFMA16(ak1, bq1, S);
                float e[4];
                #pragma unroll
                for (int reg = 0; reg < 4; reg++) e[reg] = __expf(S[reg] * SCALE_);
                if (masked) {
                    #pragma unroll
                    for (int reg = 0; reg < 4; reg++) {
                        int s = s0 + c * 16 + quad * 4 + reg;
                        if (t < s) e[reg] = 0.f;
                    }
                }
                uint2 u;
                u.x = pk2(e[0], e[1]);
                u.y = pk2(e[2], e[3]);
                *(uint2*)&Ps[(wv * 16 + lm) * 72 + c * 16 + quad * 4] = u;
            }
            // PV: A = P (wave-local rows), B = Vt
            b8v ap0 = *(const b8v*)&Ps[(wv * 16 + lm) * 72 + quad * 8];
            b8v ap1 = *(const b8v*)&Ps[(wv * 16 + lm) * 72 + 32 + quad * 8];
            #pragma unroll
            for (int c = 0; c < 4; c++) {
                b8v bv0 = *(const b8v*)&Vt[buf][(c * 16 + lm) * 72 + quad * 8];
                b8v bv1 = *(const b8v*)&Vt[buf][(c * 16 + lm) * 72 + 32 + quad * 8];
                o[c] = MFMA16(ap0, bv0, o[c]);
                o[c] = MFMA16(ap1, bv1, o[c]);
            }
        }
        #pragma unroll
        for (int c = 0; c < 4; c++)
            #pragma unroll
            for (int reg = 0; reg < 4; reg++)
                attn[(size_t)(bb * T_ + tb + wv * 16 + quad * 4 + reg) * C_ + hh * 64 +
                     c * 16 + lm] = f2b(o[c][reg]);
        __syncthreads();
    }
}

extern "C" void kernel_launch(void* const* d_in, const int* in_sizes, int n_in,
                              void* d_out, int out_size, void* d_ws, size_t ws_size,
                              hipStream_t stream) {
    const float* x   = (const float*)d_in[0];
    const float* Wq  = (const float*)d_in[1];
    const float* Wk  = (const float*)d_in[2];
    const float* Wv  = (const float*)d_in[3];
    const float* Wo  = (const float*)d_in[4];
    const float* bo  = (const float*)d_in[5];
    const float* W1  = (const float*)d_in[6];
    const float* b1  = (const float*)d_in[7];
    const float* W2  = (const float*)d_in[8];
    const float* b2  = (const float*)d_in[9];
    const float* g1  = (const float*)d_in[10];
    const float* be1 = (const float*)d_in[11];
    const float* g2  = (const float*)d_in[12];
    const float* be2 = (const float*)d_in[13];
    float* out = (float*)d_out;

    // Workspace (~62 MB). Region A (32 MB) time-multiplexed:
    //   [qkvb 16MB | attn 8MB | hbuf 8MB] then reused whole as ff1 (32MB).
    // h2 (8MB) + vt (8MB) are contiguous and both dead by W2 time ->
    // reused as the two bf16 split-K partial buffers.
    char* w = (char*)d_ws;
    auto alloc = [&](size_t bytes) -> void* {
        void* p = (void*)w;
        w += (bytes + 255) & ~(size_t)255;
        return p;
    };
    bf16* regionA = (bf16*)alloc((size_t)BT_ * 2048 * sizeof(bf16));  // 32MB
    bf16* qkvb = regionA;                                // [BT][1024] (q|k)
    bf16* attn = regionA + (size_t)BT_ * 1024;           // [BT][512]
    bf16* hbuf = regionA + (size_t)BT_ * 1536;           // [BT][512]
    bf16* ff1  = regionA;                                // [BT][2048]
    bf16* x1     = (bf16*)alloc((size_t)BT_ * C_ * sizeof(bf16));
    bf16* h2     = (bf16*)alloc((size_t)BT_ * C_ * sizeof(bf16));    // -> partial 0
    bf16* vt     = (bf16*)alloc((size_t)B_ * 512 * T_ * sizeof(bf16)); // -> partial 1
    bf16* WqkvT  = (bf16*)alloc((size_t)1536 * C_ * sizeof(bf16));
    bf16* WoT    = (bf16*)alloc((size_t)C_ * C_ * sizeof(bf16));
    bf16* W1T    = (bf16*)alloc((size_t)C4_ * C_ * sizeof(bf16));
    bf16* W2T    = (bf16*)alloc((size_t)C_ * C4_ * sizeof(bf16));
    float* Lr    = (float*)alloc((size_t)B_ * H_ * T_ * sizeof(float));
    bf16* partK  = h2;  // h2(8MB)+vt(8MB) contiguous = 16MB bf16 partials

    // All weight transposes (fp32 -> bf16 [N][K]) in one launch
    transpose_all<<<768, 256, 0, stream>>>(Wq, Wk, Wv, Wo, W1, W2,
                                           WqkvT, WoT, W1T, W2T);
    // 1. h = LN(x)
    ln_kernel<float><<<BT_, 256, 0, stream>>>(x, g1, be1, hbuf);
    // 2. QKV GEMM: [8192,1536,512]; q,k -> qkvb, v -> vt (transposed)
    mfma_gemm<4><<<dim3(BT_ / 128, 1536 / 128), 256, 0, stream>>>(
        hbuf, WqkvT, nullptr, nullptr, qkvb, vt, BT_, 1536, C_);
    // 3. column-sum reciprocals (XCD-swizzled grid)
    colsum_mfma<<<dim3(B_ * H_, 8), 512, 0, stream>>>(qkvb, Lr);
    // 4. attention output (XCD-swizzled grid)
    attnout_mfma<<<dim3(B_ * H_, 8), 512, 0, stream>>>(qkvb, vt, Lr, attn);
    // 5. x1 = x + attn @ Wo + bo
    mfma_gemm2<<<dim3(BT_ / 128, C_ / 128), 512, 0, stream>>>(
        attn, WoT, bo, x, x1, BT_, C_, C_);
    // 6. h2 = LN(x1)
    ln_kernel<bf16><<<BT_, 256, 0, stream>>>(x1, g2, be2, h2);
    // 7. ff1 = relu(h2 @ W1 + b1)
    mfma_gemm<1><<<dim3(BT_ / 128, C4_ / 128), 256, 0, stream>>>(
        h2, W1T, b1, ff1, nullptr, nullptr, BT_, C4_, C_);
    // 8a. W2 split-K: partials (512 blocks -> 2/CU)
    mfma_gemm_sk<<<dim3(BT_ / 128, C_ / 128, 2), 256, 0, stream>>>(
        ff1, W2T, partK, BT_, C_, C4_, C4_ / 2);
    // 8b. out = p0 + p1 + b2 + x1
    reduce_w2<<<(BT_ * C_) / (256 * 4), 256, 0, stream>>>(partK, b2, x1, out);
}

// Round 9
// 277.067 us; speedup vs baseline: 13.1912x; 1.0309x over previous
//
#include <hip/hip_runtime.h>
#include <hip/hip_bf16.h>

// Block_4776003633552: transformer block, B=4 T=2048 C=512 H=8 D=64. fp32 I/O.
// Reference quirks: scale = C^-0.5; softmax over QUERY axis (axis=-2) =>
//   out_t = sum_{s<=t} exp(sc*q_t.k_s) * v_s / L_s,  L_s = sum_{t>=s} exp(sc*q_t.k_s).
// Round 9: attention kernels were LDS-BW-bound (160 b128/CU-iter ~= 27us of the
// 46.5). New 2-D wave tiling: attnout waves = 4(t)x2(s) so K/V frag reads halve;
// Q frags hoisted to regs per strip; O cross-wave (s-half) reduction once/strip.
// colsum: K frags strip-resident in regs; Q frag reads 4/iter. GEMMs unchanged.

typedef __hip_bfloat16 bf16;
typedef __bf16 b8v __attribute__((ext_vector_type(8)));   // MFMA A/B fragment (8 bf16)
typedef float  f32x4 __attribute__((ext_vector_type(4))); // MFMA C/D fragment
typedef short  s8v  __attribute__((ext_vector_type(8)));  // 16B bf16 copy chunk
typedef short  s4v  __attribute__((ext_vector_type(4)));  // 8B packed chunk

#define B_   4
#define T_   2048
#define C_   512
#define H_   8
#define D_   64
#define BT_  (B_ * T_)
#define C4_  (4 * C_)
#define EPS_ 1e-5f
#define SCALE_ 0.04419417382415922f  // 1/sqrt(512)

#define MFMA16(a, b, c) __builtin_amdgcn_mfma_f32_16x16x32_bf16(a, b, c, 0, 0, 0)

static __device__ __forceinline__ float b2f(bf16 x) { return __bfloat162float(x); }
static __device__ __forceinline__ bf16  f2b(float x) { return __float2bfloat16(x); }
static __device__ __forceinline__ float s2f(short x) {
    return b2f(__builtin_bit_cast(bf16, x));
}
// packed 2xfp32 -> 2xbf16 (v_cvt_pk_bf16_f32); memcpy because __hip_bfloat162
// is not trivially copyable (bit_cast rejected).
static __device__ __forceinline__ unsigned int pk2(float a, float b) {
    float2 f;
    f.x = a;
    f.y = b;
    __hip_bfloat162 h = __float22bfloat162_rn(f);
    unsigned int u;
    __builtin_memcpy(&u, &h, 4);
    return u;
}

// ---------------- LayerNorm over C=512, one block per row ----------------
static __device__ __forceinline__ float ldv(const float* p) { return *p; }
static __device__ __forceinline__ float ldv(const bf16* p)  { return b2f(*p); }

template <typename TIN>
__global__ __launch_bounds__(256) void ln_kernel(const TIN* __restrict__ x,
                                                 const float* __restrict__ g,
                                                 const float* __restrict__ be,
                                                 bf16* __restrict__ out) {
    const int row = blockIdx.x;
    const int tid = threadIdx.x;
    const TIN* xr = x + (size_t)row * C_;
    float v0 = ldv(xr + tid * 2);
    float v1 = ldv(xr + tid * 2 + 1);
    float s = v0 + v1;
    float sq = v0 * v0 + v1 * v1;
    #pragma unroll
    for (int o = 32; o > 0; o >>= 1) {
        s += __shfl_down(s, o);
        sq += __shfl_down(sq, o);
    }
    __shared__ float ws[8], wsq[8];
    const int wid = tid >> 6, lane = tid & 63;
    if (lane == 0) { ws[wid] = s; wsq[wid] = sq; }
    __syncthreads();
    if (tid == 0) {
        float ts = 0.f, tq = 0.f;
        #pragma unroll
        for (int i = 0; i < 4; i++) { ts += ws[i]; tq += wsq[i]; }
        float mu = ts * (1.f / C_);
        float var = tq * (1.f / C_) - mu * mu;
        ws[4] = mu;
        wsq[4] = rsqrtf(var + EPS_);
    }
    __syncthreads();
    const float mu = ws[4], rstd = wsq[4];
    bf16* orow = out + (size_t)row * C_;
    orow[tid * 2]     = f2b((v0 - mu) * rstd * g[tid * 2]     + be[tid * 2]);
    orow[tid * 2 + 1] = f2b((v1 - mu) * rstd * g[tid * 2 + 1] + be[tid * 2 + 1]);
}

// ---------------- All weight transposes in one launch (768 blocks) ----------------
__global__ __launch_bounds__(256) void transpose_all(const float* __restrict__ Wq,
                                                     const float* __restrict__ Wk,
                                                     const float* __restrict__ Wv,
                                                     const float* __restrict__ Wo,
                                                     const float* __restrict__ W1,
                                                     const float* __restrict__ W2,
                                                     bf16* __restrict__ WqkvT,
                                                     bf16* __restrict__ WoT,
                                                     bf16* __restrict__ W1T,
                                                     bf16* __restrict__ W2T) {
    __shared__ float Ts[64][65];
    const int tid = threadIdx.x;
    const int id = blockIdx.x;
    if (id < 192) {
        const int sub = id / 64, rem = id % 64;
        const int x = rem & 7, hh = rem >> 3;
        const float* src = (sub == 0 ? Wq : sub == 1 ? Wk : Wv) + (size_t)hh * C_ * D_;
        bf16* dst = WqkvT + (size_t)sub * 512 * C_;
        const int c0 = x * 64;
        #pragma unroll
        for (int p = 0; p < 16; p++) {
            int idx = p * 256 + tid, i = idx >> 6, j = idx & 63;
            Ts[i][j] = src[(size_t)(c0 + i) * D_ + j];
        }
        __syncthreads();
        #pragma unroll
        for (int p = 0; p < 16; p++) {
            int idx = p * 256 + tid, j = idx >> 6, i = idx & 63;
            dst[(size_t)(hh * 64 + j) * C_ + c0 + i] = f2b(Ts[i][j]);
        }
    } else {
        const float* src;
        bf16* dst;
        int r0, c0, R, Cc;
        if (id < 256) {
            int rem = id - 192;
            src = Wo; dst = WoT; R = 512; Cc = 512;
            r0 = (rem & 7) * 64; c0 = (rem >> 3) * 64;
        } else if (id < 512) {
            int rem = id - 256;
            src = W1; dst = W1T; R = 512; Cc = 2048;
            r0 = (rem & 7) * 64; c0 = (rem >> 3) * 64;
        } else {
            int rem = id - 512;
            src = W2; dst = W2T; R = 2048; Cc = 512;
            r0 = (rem & 31) * 64; c0 = (rem >> 5) * 64;
        }
        #pragma unroll
        for (int p = 0; p < 16; p++) {
            int idx = p * 256 + tid, i = idx >> 6, j = idx & 63;
            Ts[i][j] = src[(size_t)(r0 + i) * Cc + c0 + j];
        }
        __syncthreads();
        #pragma unroll
        for (int p = 0; p < 16; p++) {
            int idx = p * 256 + tid, j = idx >> 6, i = idx & 63;
            dst[(size_t)(c0 + j) * R + r0 + i] = f2b(Ts[i][j]);
        }
    }
}

// ---------------- MFMA GEMM (256 thr): C[M,N] = A[M,K] @ Bt[N,K]^T ----------------
// 128x128 tile, BK=32, 4 waves (2x2 of 64x64), 4x4 mfma tiles/wave.
// MODE 1: +bias +relu -> bf16.  MODE 4: QKV split (q,k -> qkvb; v -> vt).
template <int MODE>
__global__ __launch_bounds__(256) void mfma_gemm(const bf16* __restrict__ A,
                                                 const bf16* __restrict__ Bt,
                                                 const float* __restrict__ bias,
                                                 bf16* __restrict__ outb,
                                                 bf16* __restrict__ qkvb,
                                                 bf16* __restrict__ vt,
                                                 int M, int N, int K) {
    __shared__ short As[128 * 32];
    __shared__ short Bs[128 * 32];
    const int tid = threadIdx.x;
    const int lane = tid & 63, wv = tid >> 6;
    const int wm = wv >> 1, wn = wv & 1;
    const int m0 = blockIdx.x * 128, n0 = blockIdx.y * 128;
    const int lrow = lane >> 2, lk = (lane & 3) * 8;
    const int lm = lane & 15, quad = lane >> 4;

    f32x4 acc[4][4];
    #pragma unroll
    for (int r = 0; r < 4; r++)
        #pragma unroll
        for (int c = 0; c < 4; c++) {
            f32x4 z = {0.f, 0.f, 0.f, 0.f};
            acc[r][c] = z;
        }

    for (int k0 = 0; k0 < K; k0 += 32) {
        #pragma unroll
        for (int cc = 0; cc < 2; cc++) {
            const int row = cc * 64 + wv * 16 + lrow;
            const bf16* ga = A + (size_t)(m0 + row) * K + k0 + lk;
            __builtin_amdgcn_global_load_lds(
                (const __attribute__((address_space(1))) void*)ga,
                (__attribute__((address_space(3))) void*)&As[(cc * 64 + wv * 16) * 32],
                16, 0, 0);
            const bf16* gb = Bt + (size_t)(n0 + row) * K + k0 + lk;
            __builtin_amdgcn_global_load_lds(
                (const __attribute__((address_space(1))) void*)gb,
                (__attribute__((address_space(3))) void*)&Bs[(cc * 64 + wv * 16) * 32],
                16, 0, 0);
        }
        __syncthreads();
        b8v af[4], bfr[4];
        #pragma unroll
        for (int r = 0; r < 4; r++)
            af[r] = *(const b8v*)&As[(wm * 64 + r * 16 + lm) * 32 + quad * 8];
        #pragma unroll
        for (int c = 0; c < 4; c++)
            bfr[c] = *(const b8v*)&Bs[(wn * 64 + c * 16 + lm) * 32 + quad * 8];
        #pragma unroll
        for (int r = 0; r < 4; r++)
            #pragma unroll
            for (int c = 0; c < 4; c++)
                acc[r][c] = MFMA16(af[r], bfr[c], acc[r][c]);
        __syncthreads();
    }

    #pragma unroll
    for (int r = 0; r < 4; r++) {
        const int mbase = m0 + wm * 64 + r * 16 + quad * 4;
        #pragma unroll
        for (int c = 0; c < 4; c++) {
            const int n = n0 + wn * 64 + c * 16 + lm;
            #pragma unroll
            for (int reg = 0; reg < 4; reg++) {
                const int m = mbase + reg;
                float v = acc[r][c][reg];
                if (MODE == 1) {
                    v += bias[n];
                    v = fmaxf(v, 0.f);
                    outb[(size_t)m * N + n] = f2b(v);
                } else {  // MODE 4: QKV
                    if (n < 1024) {
                        qkvb[(size_t)m * 1024 + n] = f2b(v);
                    } else {
                        vt[((size_t)(m >> 11) * 512 + (n - 1024)) * T_ + (m & (T_ - 1))] =
                            f2b(v);
                    }
                }
            }
        }
    }
}

// ---------------- Split-K MFMA GEMM: partial[z] = A[:, zKh:(z+1)Kh] @ Bt^T ----------------
__global__ __launch_bounds__(256) void mfma_gemm_sk(const bf16* __restrict__ A,
                                                    const bf16* __restrict__ Bt,
                                                    bf16* __restrict__ part,
                                                    int M, int N, int K, int Khalf) {
    __shared__ short As[128 * 32];
    __shared__ short Bs[128 * 32];
    const int tid = threadIdx.x;
    const int lane = tid & 63, wv = tid >> 6;
    const int wm = wv >> 1, wn = wv & 1;
    const int m0 = blockIdx.x * 128, n0 = blockIdx.y * 128;
    const int kbase = blockIdx.z * Khalf;
    const int lrow = lane >> 2, lk = (lane & 3) * 8;
    const int lm = lane & 15, quad = lane >> 4;

    f32x4 acc[4][4];
    #pragma unroll
    for (int r = 0; r < 4; r++)
        #pragma unroll
        for (int c = 0; c < 4; c++) {
            f32x4 z = {0.f, 0.f, 0.f, 0.f};
            acc[r][c] = z;
        }

    for (int kk = 0; kk < Khalf; kk += 32) {
        const int k0 = kbase + kk;
        #pragma unroll
        for (int cc = 0; cc < 2; cc++) {
            const int row = cc * 64 + wv * 16 + lrow;
            const bf16* ga = A + (size_t)(m0 + row) * K + k0 + lk;
            __builtin_amdgcn_global_load_lds(
                (const __attribute__((address_space(1))) void*)ga,
                (__attribute__((address_space(3))) void*)&As[(cc * 64 + wv * 16) * 32],
                16, 0, 0);
            const bf16* gb = Bt + (size_t)(n0 + row) * K + k0 + lk;
            __builtin_amdgcn_global_load_lds(
                (const __attribute__((address_space(1))) void*)gb,
                (__attribute__((address_space(3))) void*)&Bs[(cc * 64 + wv * 16) * 32],
                16, 0, 0);
        }
        __syncthreads();
        b8v af[4], bfr[4];
        #pragma unroll
        for (int r = 0; r < 4; r++)
            af[r] = *(const b8v*)&As[(wm * 64 + r * 16 + lm) * 32 + quad * 8];
        #pragma unroll
        for (int c = 0; c < 4; c++)
            bfr[c] = *(const b8v*)&Bs[(wn * 64 + c * 16 + lm) * 32 + quad * 8];
        #pragma unroll
        for (int r = 0; r < 4; r++)
            #pragma unroll
            for (int c = 0; c < 4; c++)
                acc[r][c] = MFMA16(af[r], bfr[c], acc[r][c]);
        __syncthreads();
    }

    bf16* pz = part + (size_t)blockIdx.z * M * N;
    #pragma unroll
    for (int r = 0; r < 4; r++) {
        const int mbase = m0 + wm * 64 + r * 16 + quad * 4;
        #pragma unroll
        for (int c = 0; c < 4; c++) {
            const int n = n0 + wn * 64 + c * 16 + lm;
            #pragma unroll
            for (int reg = 0; reg < 4; reg++)
                pz[(size_t)(mbase + reg) * N + n] = f2b(acc[r][c][reg]);
        }
    }
}

// ---------------- reduce: out = p0 + p1 + bias + res (fp32 out) ----------------
__global__ __launch_bounds__(256) void reduce_w2(const bf16* __restrict__ part,
                                                 const float* __restrict__ bias,
                                                 const bf16* __restrict__ res,
                                                 float* __restrict__ out) {
    const size_t i = ((size_t)blockIdx.x * 256 + threadIdx.x) * 4;
    const int n = (int)(i & (C_ - 1));
    s4v a = *(const s4v*)(part + i);
    s4v b = *(const s4v*)(part + (size_t)BT_ * C_ + i);
    s4v rv = *(const s4v*)(res + i);
    float4 bs = *(const float4*)(bias + n);
    float4 o;
    o.x = s2f(a[0]) + s2f(b[0]) + bs.x + s2f(rv[0]);
    o.y = s2f(a[1]) + s2f(b[1]) + bs.y + s2f(rv[1]);
    o.z = s2f(a[2]) + s2f(b[2]) + bs.z + s2f(rv[2]);
    o.w = s2f(a[3]) + s2f(b[3]) + bs.w + s2f(rv[3]);
    *(float4*)(out + i) = o;
}

// ---------------- MFMA GEMM (512 thr): Wo (+bias +fp32 res -> bf16) ----------------
__global__ __launch_bounds__(512) void mfma_gemm2(const bf16* __restrict__ A,
                                                  const bf16* __restrict__ Bt,
                                                  const float* __restrict__ bias,
                                                  const float* __restrict__ resf,
                                                  bf16* __restrict__ outb,
                                                  int M, int N, int K) {
    __shared__ short As[128 * 32];
    __shared__ short Bs[128 * 32];
    const int tid = threadIdx.x;
    const int lane = tid & 63, wv = tid >> 6;       // 8 waves
    const int wm = wv >> 2, wn = wv & 3;            // 2 x 4
    const int m0 = blockIdx.x * 128, n0 = blockIdx.y * 128;
    const int lm = lane & 15, quad = lane >> 4;

    f32x4 acc[4][2];
    #pragma unroll
    for (int r = 0; r < 4; r++)
        #pragma unroll
        for (int c = 0; c < 2; c++) {
            f32x4 z = {0.f, 0.f, 0.f, 0.f};
            acc[r][c] = z;
        }

    for (int k0 = 0; k0 < K; k0 += 32) {
        const int row = wv * 16 + (lane >> 2);
        const int lk = (lane & 3) * 8;
        const bf16* ga = A + (size_t)(m0 + row) * K + k0 + lk;
        __builtin_amdgcn_global_load_lds(
            (const __attribute__((address_space(1))) void*)ga,
            (__attribute__((address_space(3))) void*)&As[(wv * 16) * 32],
            16, 0, 0);
        const bf16* gb = Bt + (size_t)(n0 + row) * K + k0 + lk;
        __builtin_amdgcn_global_load_lds(
            (const __attribute__((address_space(1))) void*)gb,
            (__attribute__((address_space(3))) void*)&Bs[(wv * 16) * 32],
            16, 0, 0);
        __syncthreads();
        b8v af[4], bfr[2];
        #pragma unroll
        for (int r = 0; r < 4; r++)
            af[r] = *(const b8v*)&As[(wm * 64 + r * 16 + lm) * 32 + quad * 8];
        #pragma unroll
        for (int c = 0; c < 2; c++)
            bfr[c] = *(const b8v*)&Bs[(wn * 32 + c * 16 + lm) * 32 + quad * 8];
        #pragma unroll
        for (int r = 0; r < 4; r++)
            #pragma unroll
            for (int c = 0; c < 2; c++)
                acc[r][c] = MFMA16(af[r], bfr[c], acc[r][c]);
        __syncthreads();
    }

    #pragma unroll
    for (int r = 0; r < 4; r++) {
        const int mbase = m0 + wm * 64 + r * 16 + quad * 4;
        #pragma unroll
        for (int c = 0; c < 2; c++) {
            const int n = n0 + wn * 32 + c * 16 + lm;
            #pragma unroll
            for (int reg = 0; reg < 4; reg++) {
                const int m = mbase + reg;
                float v = acc[r][c][reg] + bias[n] + resf[(size_t)m * N + n];
                outb[(size_t)m * N + n] = f2b(v);
            }
        }
    }
}

// ---------------- Pass 1: Lr[s] = 1 / sum_{t>=s} exp(sc*q_t.k_s) ----------------
// Wave grid 4(t-quarter) x 2(s-half of the 128-key strip). K B-frags hoisted to
// registers once per strip (8 reads); Q A-frags 4 reads/iter. S = Q.K^T.
__global__ __launch_bounds__(512) void colsum_mfma(const bf16* __restrict__ qkv,
                                                   float* __restrict__ Lr) {
    __shared__ short Ks[128 * 72];
    __shared__ short Qs[2][128 * 72];
    __shared__ float red[4][128];
    const int tid = threadIdx.x, lane = tid & 63, wv = tid >> 6;
    const int wq = wv >> 1, wk = wv & 1;
    const int lm = lane & 15, quad = lane >> 4;
    const int bh = blockIdx.x, bb = bh >> 3, hh = bh & 7;
    const bf16* qbase = qkv + (size_t)bb * T_ * 1024 + hh * 64;
    const bf16* kbase = qbase + 512;
    const int rA = tid >> 3, rB = 64 + (tid >> 3), ch = tid & 7;
    for (int half = 0; half < 2; half++) {
        const int strip = half ? 15 - (int)blockIdx.y : (int)blockIdx.y;
        const int s0 = strip * 128;
        // stage resident K (visible after iter-0 barrier)
        *(s8v*)&Ks[rA * 72 + ch * 8] =
            *(const s8v*)(kbase + (size_t)(s0 + rA) * 1024 + ch * 8);
        *(s8v*)&Ks[rB * 72 + ch * 8] =
            *(const s8v*)(kbase + (size_t)(s0 + rB) * 1024 + ch * 8);
        // preload Q tile 0
        s8v qrA = *(const s8v*)(qbase + (size_t)(s0 + rA) * 1024 + ch * 8);
        s8v qrB = *(const s8v*)(qbase + (size_t)(s0 + rB) * 1024 + ch * 8);
        b8v bk[4][2];  // strip-resident K fragments (s = wk*64 + c*16 + lm)
        float csum[4] = {};
        const int niter = (T_ - s0) / 128;
        for (int it = 0; it < niter; it++) {
            const int buf = it & 1;
            *(s8v*)&Qs[buf][rA * 72 + ch * 8] = qrA;
            *(s8v*)&Qs[buf][rB * 72 + ch * 8] = qrB;
            __syncthreads();
            if (it == 0) {
                #pragma unroll
                for (int c = 0; c < 4; c++)
                    #pragma unroll
                    for (int k = 0; k < 2; k++)
                        bk[c][k] = *(const b8v*)&Ks[(wk * 64 + c * 16 + lm) * 72 +
                                                    k * 32 + quad * 8];
            }
            if (it + 1 < niter) {
                const int t1 = s0 + (it + 1) * 128;
                qrA = *(const s8v*)(qbase + (size_t)(t1 + rA) * 1024 + ch * 8);
                qrB = *(const s8v*)(qbase + (size_t)(t1 + rB) * 1024 + ch * 8);
            }
            const int t0 = s0 + it * 128;
            b8v aq[2][2];
            #pragma unroll
            for (int r = 0; r < 2; r++)
                #pragma unroll
                for (int k = 0; k < 2; k++)
                    aq[r][k] = *(const b8v*)&Qs[buf][(wq * 32 + r * 16 + lm) * 72 +
                                                     k * 32 + quad * 8];
            if (it == 0) {  // diagonal: causal mask needed
                #pragma unroll
                for (int r = 0; r < 2; r++)
                    #pragma unroll
                    for (int c = 0; c < 4; c++) {
                        f32x4 S = {0.f, 0.f, 0.f, 0.f};
                        S = MFMA16(aq[r][0], bk[c][0], S);
                        S = MFMA16(aq[r][1], bk[c][1], S);
                        const int s = s0 + wk * 64 + c * 16 + lm;
                        #pragma unroll
                        for (int reg = 0; reg < 4; reg++) {
                            int t = t0 + wq * 32 + r * 16 + quad * 4 + reg;
                            if (t >= s) csum[c] += __expf(S[reg] * SCALE_);
                        }
                    }
            } else {  // strictly below diagonal: no mask
                #pragma unroll
                for (int r = 0; r < 2; r++)
                    #pragma unroll
                    for (int c = 0; c < 4; c++) {
                        f32x4 S = {0.f, 0.f, 0.f, 0.f};
                        S = MFMA16(aq[r][0], bk[c][0], S);
                        S = MFMA16(aq[r][1], bk[c][1], S);
                        csum[c] += __expf(S[0] * SCALE_) + __expf(S[1] * SCALE_) +
                                   __expf(S[2] * SCALE_) + __expf(S[3] * SCALE_);
                    }
            }
        }
        __syncthreads();  // all Ks/Qs reads done before reduction & restage
        #pragma unroll
        for (int c = 0; c < 4; c++) {
            float v = csum[c];
            v += __shfl_xor(v, 16);
            v += __shfl_xor(v, 32);
            if (lane < 16) red[wq][wk * 64 + c * 16 + lane] = v;
        }
        __syncthreads();
        if (tid < 128) {
            float s = red[0][tid] + red[1][tid] + red[2][tid] + red[3][tid];
            Lr[(size_t)bh * T_ + s0 + tid] = 1.0f / s;
        }
        __syncthreads();
    }
}

// ---------------- Pass 2: out_t = sum_{s<=t} exp(sc*q_t.k_s) * (v_s * Lr_s) ----------------
// Wave grid 4(t: 32 rows) x 2(s-half of the 64-key tile). Q B-frags hoisted per
// strip; each wave reads only its K/V half -> LDS reads halved. O is partial
// over the s-split -> cross-wave f32x4 LDS reduction once per strip.
__global__ __launch_bounds__(512) void attnout_mfma(const bf16* __restrict__ qkv,
                                                    const bf16* __restrict__ vt,
                                                    const float* __restrict__ Lr,
                                                    bf16* __restrict__ attn) {
    __shared__ short Qs[128 * 72];
    __shared__ short Ps[128 * 72];
    __shared__ short Ks[2][64 * 72];
    __shared__ short Vt[2][64 * 72];
    __shared__ float Ored[64 * 132];  // [d 64][t 128+4 pad] fp32 partial O
    const int tid = threadIdx.x, lane = tid & 63, wv = tid >> 6;
    const int wm = wv >> 1, wn = wv & 1;
    const int lm = lane & 15, quad = lane >> 4;
    const int bh = blockIdx.x, bb = bh >> 3, hh = bh & 7;
    const bf16* qbase = qkv + (size_t)bb * T_ * 1024 + hh * 64;
    const bf16* kbase = qbase + 512;
    const bf16* vtb = vt + ((size_t)bb * 512 + hh * 64) * T_;
    const float* Lrb = Lr + (size_t)bh * T_;
    const int r_ = tid >> 3, ch = tid & 7;
    for (int half = 0; half < 2; half++) {
        const int strip = half ? 15 - (int)blockIdx.y : (int)blockIdx.y;
        const int tb = strip * 128;
        // stage Q strip (visible after iter-0 barrier)
        #pragma unroll
        for (int cc = 0; cc < 2; cc++) {
            int idx = cc * 512 + tid, qr = idx >> 3, qc = idx & 7;
            *(s8v*)&Qs[qr * 72 + qc * 8] =
                *(const s8v*)(qbase + (size_t)(tb + qr) * 1024 + qc * 8);
        }
        // preload K/V/Lr tile 0
        s8v kreg = *(const s8v*)(kbase + (size_t)r_ * 1024 + ch * 8);
        s8v vreg = *(const s8v*)(vtb + (size_t)r_ * T_ + ch * 8);
        float4 lr0 = *(const float4*)(Lrb + ch * 8);
        float4 lr1 = *(const float4*)(Lrb + ch * 8 + 4);
        b8v bq[2][2];  // strip-resident Q fragments (t = wm*32 + r*16 + lm)
        f32x4 o[2][4];
        #pragma unroll
        for (int r = 0; r < 2; r++)
            #pragma unroll
            for (int c = 0; c < 4; c++) {
                f32x4 z = {0.f, 0.f, 0.f, 0.f};
                o[r][c] = z;
            }
        const int niter = (tb + 128) / 64;
        for (int it = 0; it < niter; it++) {
            const int s0 = it * 64, buf = it & 1;
            // scale V by 1/L (packed cvt) and commit staged tile
            uint4 vs;
            vs.x = pk2(s2f(vreg[0]) * lr0.x, s2f(vreg[1]) * lr0.y);
            vs.y = pk2(s2f(vreg[2]) * lr0.z, s2f(vreg[3]) * lr0.w);
            vs.z = pk2(s2f(vreg[4]) * lr1.x, s2f(vreg[5]) * lr1.y);
            vs.w = pk2(s2f(vreg[6]) * lr1.z, s2f(vreg[7]) * lr1.w);
            *(s8v*)&Ks[buf][r_ * 72 + ch * 8] = kreg;
            *(uint4*)&Vt[buf][r_ * 72 + ch * 8] = vs;
            __syncthreads();
            if (it == 0) {
                #pragma unroll
                for (int r = 0; r < 2; r++)
                    #pragma unroll
                    for (int k = 0; k < 2; k++)
                        bq[r][k] = *(const b8v*)&Qs[(wm * 32 + r * 16 + lm) * 72 +
                                                    k * 32 + quad * 8];
            }
            if (it + 1 < niter) {
                const int s1 = s0 + 64;
                kreg = *(const s8v*)(kbase + (size_t)(s1 + r_) * 1024 + ch * 8);
                vreg = *(const s8v*)(vtb + (size_t)r_ * T_ + s1 + ch * 8);
                lr0 = *(const float4*)(Lrb + s1 + ch * 8);
                lr1 = *(const float4*)(Lrb + s1 + ch * 8 + 4);
            }
            // S^T = K . Q^T over this wave's s-half (wn*32, 32 keys)
            b8v ak[2][2];
            #pragma unroll
            for (int c = 0; c < 2; c++)
                #pragma unroll
                for (int k = 0; k < 2; k++)
                    ak[c][k] = *(const b8v*)&Ks[buf][(wn * 32 + c * 16 + lm) * 72 +
                                                     k * 32 + quad * 8];
            const bool masked = (s0 >= tb);  // only diagonal-region tiles
            #pragma unroll
            for (int r = 0; r < 2; r++) {
                const int t = tb + wm * 32 + r * 16 + lm;
                #pragma unroll
                for (int c = 0; c < 2; c++) {
                    f32x4 S = {0.f, 0.f, 0.f, 0.f};
                    S = MFMA16(ak[c][0], bq[r][0], S);
                    S = MFMA16(ak[c][1], bq[r][1], S);
                    float e[4];
                    #pragma unroll
                    for (int reg = 0; reg < 4; reg++) e[reg] = __expf(S[reg] * SCALE_);
                    if (masked) {
                        #pragma unroll
                        for (int reg = 0; reg < 4; reg++) {
                            int s = s0 + wn * 32 + c * 16 + quad * 4 + reg;
                            if (t < s) e[reg] = 0.f;
                        }
                    }
                    uint2 u;
                    u.x = pk2(e[0], e[1]);
                    u.y = pk2(e[2], e[3]);
                    *(uint2*)&Ps[(wm * 32 + r * 16 + lm) * 72 + wn * 32 + c * 16 +
                                 quad * 4] = u;
                }
            }
            // PV over this wave's s-half: A = P (wave-local), B = Vt
            #pragma unroll
            for (int r = 0; r < 2; r++) {
                b8v ap = *(const b8v*)&Ps[(wm * 32 + r * 16 + lm) * 72 + wn * 32 +
                                          quad * 8];
                #pragma unroll
                for (int c = 0; c < 4; c++) {
                    b8v bv = *(const b8v*)&Vt[buf][(c * 16 + lm) * 72 + wn * 32 +
                                                   quad * 8];
                    o[r][c] = MFMA16(ap, bv, o[r][c]);
                }
            }
        }
        // cross-wave O reduction (s-halves) once per strip
        if (wn == 1) {
            #pragma unroll
            for (int r = 0; r < 2; r++)
                #pragma unroll
                for (int c = 0; c < 4; c++)
                    *(f32x4*)&Ored[(c * 16 + lm) * 132 + wm * 32 + r * 16 + quad * 4] =
                        o[r][c];
        }
        __syncthreads();
        if (wn == 0) {
            #pragma unroll
            for (int r = 0; r < 2; r++)
                #pragma unroll
                for (int c = 0; c < 4; c++) {
                    f32x4 p = *(const f32x4*)&Ored[(c * 16 + lm) * 132 + wm * 32 +
                                                   r * 16 + quad * 4];
                    #pragma unroll
                    for (int reg = 0; reg < 4; reg++)
                        attn[(size_t)(bb * T_ + tb + wm * 32 + r * 16 + quad * 4 +
                                      reg) * C_ + hh * 64 + c * 16 + lm] =
                            f2b(o[r][c][reg] + p[reg]);
                }
        }
        __syncthreads();  // protect Qs/Ks/Vt/Ored restage in next half
    }
}

extern "C" void kernel_launch(void* const* d_in, const int* in_sizes, int n_in,
                              void* d_out, int out_size, void* d_ws, size_t ws_size,
                              hipStream_t stream) {
    const float* x   = (const float*)d_in[0];
    const float* Wq  = (const float*)d_in[1];
    const float* Wk  = (const float*)d_in[2];
    const float* Wv  = (const float*)d_in[3];
    const float* Wo  = (const float*)d_in[4];
    const float* bo  = (const float*)d_in[5];
    const float* W1  = (const float*)d_in[6];
    const float* b1  = (const float*)d_in[7];
    const float* W2  = (const float*)d_in[8];
    const float* b2  = (const float*)d_in[9];
    const float* g1  = (const float*)d_in[10];
    const float* be1 = (const float*)d_in[11];
    const float* g2  = (const float*)d_in[12];
    const float* be2 = (const float*)d_in[13];
    float* out = (float*)d_out;

    // Workspace (~62 MB). Region A (32 MB) time-multiplexed:
    //   [qkvb 16MB | attn 8MB | hbuf 8MB] then reused whole as ff1 (32MB).
    // h2 (8MB) + vt (8MB) contiguous, dead by W2 time -> split-K partials.
    char* w = (char*)d_ws;
    auto alloc = [&](size_t bytes) -> void* {
        void* p = (void*)w;
        w += (bytes + 255) & ~(size_t)255;
        return p;
    };
    bf16* regionA = (bf16*)alloc((size_t)BT_ * 2048 * sizeof(bf16));  // 32MB
    bf16* qkvb = regionA;                                // [BT][1024] (q|k)
    bf16* attn = regionA + (size_t)BT_ * 1024;           // [BT][512]
    bf16* hbuf = regionA + (size_t)BT_ * 1536;           // [BT][512]
    bf16* ff1  = regionA;                                // [BT][2048]
    bf16* x1     = (bf16*)alloc((size_t)BT_ * C_ * sizeof(bf16));
    bf16* h2     = (bf16*)alloc((size_t)BT_ * C_ * sizeof(bf16));    // -> partial 0
    bf16* vt     = (bf16*)alloc((size_t)B_ * 512 * T_ * sizeof(bf16)); // -> partial 1
    bf16* WqkvT  = (bf16*)alloc((size_t)1536 * C_ * sizeof(bf16));
    bf16* WoT    = (bf16*)alloc((size_t)C_ * C_ * sizeof(bf16));
    bf16* W1T    = (bf16*)alloc((size_t)C4_ * C_ * sizeof(bf16));
    bf16* W2T    = (bf16*)alloc((size_t)C_ * C4_ * sizeof(bf16));
    float* Lr    = (float*)alloc((size_t)B_ * H_ * T_ * sizeof(float));
    bf16* partK  = h2;  // h2(8MB)+vt(8MB) contiguous = 16MB bf16 partials

    // All weight transposes (fp32 -> bf16 [N][K]) in one launch
    transpose_all<<<768, 256, 0, stream>>>(Wq, Wk, Wv, Wo, W1, W2,
                                           WqkvT, WoT, W1T, W2T);
    // 1. h = LN(x)
    ln_kernel<float><<<BT_, 256, 0, stream>>>(x, g1, be1, hbuf);
    // 2. QKV GEMM: [8192,1536,512]; q,k -> qkvb, v -> vt (transposed)
    mfma_gemm<4><<<dim3(BT_ / 128, 1536 / 128), 256, 0, stream>>>(
        hbuf, WqkvT, nullptr, nullptr, qkvb, vt, BT_, 1536, C_);
    // 3. column-sum reciprocals (XCD-swizzled grid)
    colsum_mfma<<<dim3(B_ * H_, 8), 512, 0, stream>>>(qkvb, Lr);
    // 4. attention output (XCD-swizzled grid)
    attnout_mfma<<<dim3(B_ * H_, 8), 512, 0, stream>>>(qkvb, vt, Lr, attn);
    // 5. x1 = x + attn @ Wo + bo
    mfma_gemm2<<<dim3(BT_ / 128, C_ / 128), 512, 0, stream>>>(
        attn, WoT, bo, x, x1, BT_, C_, C_);
    // 6. h2 = LN(x1)
    ln_kernel<bf16><<<BT_, 256, 0, stream>>>(x1, g2, be2, h2);
    // 7. ff1 = relu(h2 @ W1 + b1)
    mfma_gemm<1><<<dim3(BT_ / 128, C4_ / 128), 256, 0, stream>>>(
        h2, W1T, b1, ff1, nullptr, nullptr, BT_, C4_, C_);
    // 8a. W2 split-K: partials (512 blocks -> 2/CU)
    mfma_gemm_sk<<<dim3(BT_ / 128, C_ / 128, 2), 256, 0, stream>>>(
        ff1, W2T, partK, BT_, C_, C4_, C4_ / 2);
    // 8b. out = p0 + p1 + b2 + x1
    reduce_w2<<<(BT_ * C_) / (256 * 4), 256, 0, stream>>>(partK, b2, x1, out);
}